// Round 1
// baseline (1755.049 us; speedup 1.0000x reference)
//
#include <hip/hip_runtime.h>

typedef unsigned short u16;
typedef float f4 __attribute__((ext_vector_type(4)));
typedef float f32x4 __attribute__((ext_vector_type(4)));
typedef short bf16x8 __attribute__((ext_vector_type(8)));
typedef u16 u16x8 __attribute__((ext_vector_type(8)));
typedef u16 u16x4 __attribute__((ext_vector_type(4)));

__device__ __forceinline__ u16 f2bf(float f){
  unsigned u = __float_as_uint(f);
  u = (u + 0x7FFFu + ((u>>16)&1u)) >> 16;
  return (u16)u;
}
__device__ __forceinline__ float bf2f(u16 u){
  return __uint_as_float(((unsigned)u)<<16);
}
__device__ __forceinline__ float gelu_f(float x){
  return 0.5f*x*(1.0f+erff(x*0.70710678118654752440f));
}

// ---------------------------------------------------------------------------
// Stage 1: fused 3x 3x3 conv + bias + GELU, writing directly into unfolded
// bf16 layouts:  Aq/Ak = [B][L=1024][CK=4096] (GEMM A operands),
//                Vc    = [B][CK=4096][L=1024] (GEMM B^T operand for attn@V).
// grid (32 ytiles, 64 cout, 4 b), block 256 = 32 wb x 8 kh. Thread computes
// one patch row (8 kw outputs) for all 3 convs.
// ---------------------------------------------------------------------------
__global__ __launch_bounds__(256,2) void conv3_fused(
    const float* __restrict__ feat,
    const float* __restrict__ w_enc, const float* __restrict__ w_k, const float* __restrict__ w_v,
    const float* __restrict__ b_enc, const float* __restrict__ b_k, const float* __restrict__ b_v,
    u16* __restrict__ Aq, u16* __restrict__ Ak, u16* __restrict__ Vc)
{
  const int yt = blockIdx.x, co = blockIdx.y, b = blockIdx.z;
  const int t = threadIdx.x, wb = t & 31, kh = t >> 5;
  const int y  = yt*8 + kh;
  const int x0 = wb*8 - 4;           // 16-float window covers x in [x0, x0+16)
  const float* fb = feat + ((long)b*64)*65536;

  float accq[8] = {0,0,0,0,0,0,0,0};
  float acck[8] = {0,0,0,0,0,0,0,0};
  float accv[8] = {0,0,0,0,0,0,0,0};
  const f4 z4 = {0.f,0.f,0.f,0.f};

  for (int ci = 0; ci < 64; ++ci){
    const float* cbase = fb + (long)ci*65536;
    float r0[16], r1[16], r2[16];
    // window chunks are wholly valid or wholly out of range (x0 === 4 mod 8):
    // chunk0 invalid iff wb==0, chunk3 invalid iff wb==31, rows guarded by y.
#define LOADROW(RR, YY) { \
    const int yy = (YY); const bool rvv = ((unsigned)yy < 256u); \
    const float* rp = cbase + yy*256 + x0; \
    f4 va = (rvv && wb>0 ) ? *(const f4*)(rp   ) : z4; \
    f4 vb = (rvv         ) ? *(const f4*)(rp+ 4) : z4; \
    f4 vc = (rvv         ) ? *(const f4*)(rp+ 8) : z4; \
    f4 vd = (rvv && wb<31) ? *(const f4*)(rp+12) : z4; \
    RR[0]=va[0];RR[1]=va[1];RR[2]=va[2];RR[3]=va[3]; \
    RR[4]=vb[0];RR[5]=vb[1];RR[6]=vb[2];RR[7]=vb[3]; \
    RR[8]=vc[0];RR[9]=vc[1];RR[10]=vc[2];RR[11]=vc[3]; \
    RR[12]=vd[0];RR[13]=vd[1];RR[14]=vd[2];RR[15]=vd[3]; }
    LOADROW(r0, y-1)
    LOADROW(r1, y  )
    LOADROW(r2, y+1)
#undef LOADROW
    const int wo = (co*64 + ci)*9;   // uniform -> scalar loads
    float we[9], wkk[9], wvv[9];
    #pragma unroll
    for (int j = 0; j < 9; ++j){ we[j]=w_enc[wo+j]; wkk[j]=w_k[wo+j]; wvv[j]=w_v[wo+j]; }
    #pragma unroll
    for (int dx = 0; dx < 3; ++dx){
      #pragma unroll
      for (int kw = 0; kw < 8; ++kw){
        const float xa = r0[kw+dx+3], xb = r1[kw+dx+3], xc = r2[kw+dx+3];
        accq[kw] += xa*we[dx]  + xb*we[3+dx]  + xc*we[6+dx];
        acck[kw] += xa*wkk[dx] + xb*wkk[3+dx] + xc*wkk[6+dx];
        accv[kw] += xa*wvv[dx] + xb*wvv[3+dx] + xc*wvv[6+dx];
      }
    }
  }
  const float be = b_enc[co], bk_ = b_k[co], bv_ = b_v[co];
  u16x8 vq, vk;
  #pragma unroll
  for (int kw = 0; kw < 8; ++kw){
    vq[kw] = f2bf(gelu_f(accq[kw] + be));
    vk[kw] = f2bf(gelu_f(acck[kw] + bk_));
  }
  const long l   = (long)b*1024 + yt*32 + wb;   // l = hb*32 + wb, hb = yt
  const int  ckb = co*64 + kh*8;                // ck = c*64 + kh*8 + kw
  *(u16x8*)(Aq + l*4096 + ckb) = vq;
  *(u16x8*)(Ak + l*4096 + ckb) = vk;
  const long vbase = ((long)b*4096 + ckb)*1024 + yt*32 + wb;
  #pragma unroll
  for (int kw = 0; kw < 8; ++kw)
    Vc[vbase + (long)kw*1024] = f2bf(gelu_f(accv[kw] + bv_));
}

// ---------------------------------------------------------------------------
// bf16 MFMA GEMM: C[b] = A[b] (MxK, row-major) * B[b]^T (B stored [N][K]).
// 128x128 tile, BK=32, 4 waves (2x2 of 64x64), 16x16x32 bf16 MFMA.
// EPI 0: fp32 store C[row*N+col].  EPI 1: fold+bf16 store (attn@V -> NCHW).
// All dims divide tile sizes exactly (M=1024, N in {1024,4096}, K in {1024,4096}).
// ---------------------------------------------------------------------------
template<int EPI>
__global__ __launch_bounds__(256,2) void gemm_bt(
    const u16* __restrict__ A, long sA,
    const u16* __restrict__ B, long sB,
    void* __restrict__ Cv, long sC,
    const int M, const int N, const int K)
{
  const int bI = blockIdx.z;
  const u16* Ab = A + (long)bI*sA;
  const u16* Bb = B + (long)bI*sB;
  const int m0 = blockIdx.x*128, n0 = blockIdx.y*128;
  __shared__ __align__(16) u16 As[128][40];   // +8 bf16 pad: 80B row stride, ~2-way banks
  __shared__ __align__(16) u16 Bs[128][40];
  const int t = threadIdx.x, lane = t & 63, wv = t >> 6;
  const int wm = (wv>>1)*64, wn = (wv&1)*64;
  const int fr = lane & 15, fo = lane >> 4;
  f32x4 acc[4][4] = {};
  // staging: 512 16B-chunks per matrix, 2 per thread
  const int c0 = t*2, c1 = t*2+1;
  const int r0_ = c0>>2, k0_ = (c0&3)*8, r1_ = c1>>2, k1_ = (c1&3)*8;
  const u16* Ag0 = Ab + (long)(m0+r0_)*K + k0_;
  const u16* Ag1 = Ab + (long)(m0+r1_)*K + k1_;
  const u16* Bg0 = Bb + (long)(n0+r0_)*K + k0_;
  const u16* Bg1 = Bb + (long)(n0+r1_)*K + k1_;
  for (int k0 = 0; k0 < K; k0 += 32){
    __syncthreads();
    *(int4*)&As[r0_][k0_] = *(const int4*)(Ag0 + k0);
    *(int4*)&As[r1_][k1_] = *(const int4*)(Ag1 + k0);
    *(int4*)&Bs[r0_][k0_] = *(const int4*)(Bg0 + k0);
    *(int4*)&Bs[r1_][k1_] = *(const int4*)(Bg1 + k0);
    __syncthreads();
    bf16x8 af[4], bfv[4];
    #pragma unroll
    for (int i = 0; i < 4; ++i){
      af[i]  = *(const bf16x8*)&As[wm + i*16 + fr][fo*8];
      bfv[i] = *(const bf16x8*)&Bs[wn + i*16 + fr][fo*8];
    }
    #pragma unroll
    for (int mi = 0; mi < 4; ++mi)
      #pragma unroll
      for (int ni = 0; ni < 4; ++ni)
        acc[mi][ni] = __builtin_amdgcn_mfma_f32_16x16x32_bf16(af[mi], bfv[ni], acc[mi][ni], 0, 0, 0);
  }
  if (EPI == 0){
    float* Cf = (float*)Cv + (long)bI*sC;
    #pragma unroll
    for (int mi = 0; mi < 4; ++mi)
      #pragma unroll
      for (int ni = 0; ni < 4; ++ni){
        const int col = n0 + wn + ni*16 + fr;
        #pragma unroll
        for (int r = 0; r < 4; ++r){
          const int row = m0 + wm + mi*16 + fo*4 + r;
          Cf[(long)row*N + col] = acc[mi][ni][r];
        }
      }
  } else {
    // fold: row=l=hb*32+wb, col=ck=c*64+kh*8+kw -> img[b][c][hb*8+kh][wb*8+kw]
    u16* O = (u16*)Cv;
    #pragma unroll
    for (int mi = 0; mi < 4; ++mi)
      #pragma unroll
      for (int ni = 0; ni < 4; ++ni){
        const int col = n0 + wn + ni*16 + fr;
        const int c = col >> 6, khh = (col>>3)&7, kww = col&7;
        #pragma unroll
        for (int r = 0; r < 4; ++r){
          const int row = m0 + wm + mi*16 + fo*4 + r;
          const int hb = row >> 5, wbb = row & 31;
          O[(((long)(bI*64 + c)*256 + hb*8 + khh)*256) + wbb*8 + kww] = f2bf(acc[mi][ni][r]);
        }
      }
  }
}

// ---------------------------------------------------------------------------
// fcq_w / fck_w fp32 -> bf16
// ---------------------------------------------------------------------------
__global__ __launch_bounds__(256) void cvt_w(
    const float* __restrict__ Wq, const float* __restrict__ Wk,
    u16* __restrict__ Oq, u16* __restrict__ Ok)
{
  const long i = ((long)blockIdx.x*256 + threadIdx.x)*4;
  const float* s = blockIdx.y ? Wk : Wq;
  u16* d = blockIdx.y ? Ok : Oq;
  f4 v = *(const f4*)&s[i];
  u16x4 o; o[0]=f2bf(v[0]); o[1]=f2bf(v[1]); o[2]=f2bf(v[2]); o[3]=f2bf(v[3]);
  *(u16x4*)&d[i] = o;
}

// ---------------------------------------------------------------------------
// BN stats over rows: X = [4096][1024] fp32; per-column sum & sumsq (atomics).
// grid 256 blocks x 16 rows each; thread t owns 4 columns.
// ---------------------------------------------------------------------------
__global__ __launch_bounds__(256) void bn_stats(
    const float* __restrict__ X, float* __restrict__ sum, float* __restrict__ sumsq)
{
  const int t = threadIdx.x;
  const long r0 = (long)blockIdx.x*16;
  f4 s = {0,0,0,0}, q = {0,0,0,0};
  for (int r = 0; r < 16; ++r){
    f4 v = *(const f4*)&X[(r0 + r)*1024 + t*4];
    s += v; q += v*v;
  }
  atomicAdd(&sum[t*4+0], s[0]); atomicAdd(&sum[t*4+1], s[1]);
  atomicAdd(&sum[t*4+2], s[2]); atomicAdd(&sum[t*4+3], s[3]);
  atomicAdd(&sumsq[t*4+0], q[0]); atomicAdd(&sumsq[t*4+1], q[1]);
  atomicAdd(&sumsq[t*4+2], q[2]); atomicAdd(&sumsq[t*4+3], q[3]);
}

__global__ void bn_fin(const float* __restrict__ sum, const float* __restrict__ sumsq,
                       const float* __restrict__ g, const float* __restrict__ beta,
                       float* __restrict__ scale, float* __restrict__ shift)
{
  const int d = blockIdx.x*256 + threadIdx.x;
  if (d >= 1024) return;
  const float m  = sum[d]   * (1.f/4096.f);
  const float vv = sumsq[d] * (1.f/4096.f) - m*m;
  const float sc = g[d] * rsqrtf(vv + 1e-5f);
  scale[d] = sc;
  shift[d] = beta[d] - m*sc;
}

__global__ __launch_bounds__(256) void bn_apply(
    const float* __restrict__ X, const float* __restrict__ scale,
    const float* __restrict__ shift, u16* __restrict__ Y)
{
  const long i = ((long)blockIdx.x*256 + threadIdx.x)*4;
  f4 v = *(const f4*)&X[i];
  const int d = (int)(i & 1023);
  const f4 sc = *(const f4*)&scale[d];
  const f4 sh = *(const f4*)&shift[d];
  v = v*sc + sh;
  u16x4 o; o[0]=f2bf(v[0]); o[1]=f2bf(v[1]); o[2]=f2bf(v[2]); o[3]=f2bf(v[3]);
  *(u16x4*)&Y[i] = o;
}

// ---------------------------------------------------------------------------
// row softmax over 1024 (scale 1/32 applied here); output bf16 attn.
// ---------------------------------------------------------------------------
__global__ __launch_bounds__(256) void softmax_k(
    const float* __restrict__ S, u16* __restrict__ P)
{
  const long row = blockIdx.x;
  const float* p = S + row*1024;
  const int t = threadIdx.x;
  f4 v = *(const f4*)&p[t*4];
  v *= 0.03125f;
  float mx = fmaxf(fmaxf(v[0],v[1]), fmaxf(v[2],v[3]));
  #pragma unroll
  for (int o = 1; o < 64; o <<= 1) mx = fmaxf(mx, __shfl_xor(mx, o));
  __shared__ float red[4], red2[4];
  if ((t & 63) == 0) red[t>>6] = mx;
  __syncthreads();
  mx = fmaxf(fmaxf(red[0],red[1]), fmaxf(red[2],red[3]));
  f4 e;
  e[0]=__expf(v[0]-mx); e[1]=__expf(v[1]-mx); e[2]=__expf(v[2]-mx); e[3]=__expf(v[3]-mx);
  float sm = e[0]+e[1]+e[2]+e[3];
  #pragma unroll
  for (int o = 1; o < 64; o <<= 1) sm += __shfl_xor(sm, o);
  if ((t & 63) == 0) red2[t>>6] = sm;
  __syncthreads();
  sm = red2[0]+red2[1]+red2[2]+red2[3];
  const float inv = 1.0f/sm;
  u16x4 o4; o4[0]=f2bf(e[0]*inv); o4[1]=f2bf(e[1]*inv); o4[2]=f2bf(e[2]*inv); o4[3]=f2bf(e[3]*inv);
  *(u16x4*)&P[row*1024 + t*4] = o4;
}

// ---------------------------------------------------------------------------
// ff1: h1[b][o][p] = gelu(sum_c X[b][c][p]*W1[o][c] + b1[o]); X bf16 NCHW.
// block = 256 threads, 2 pixels each (512 px/block); W1 staged in LDS (64KB).
// ---------------------------------------------------------------------------
__global__ __launch_bounds__(256,2) void ff1_k(
    const u16* __restrict__ X, const float* __restrict__ W1,
    const float* __restrict__ B1, u16* __restrict__ H)
{
  __shared__ float wl[16384];
  const int t = threadIdx.x;
  for (int i = t; i < 16384; i += 256) wl[i] = W1[i];
  __syncthreads();
  const int b = blockIdx.y;
  const long p = (long)blockIdx.x*512 + t;
  const u16* xb = X + (long)b*64*65536;
  float x0[64], x1[64];
  #pragma unroll
  for (int c = 0; c < 64; ++c){
    x0[c] = bf2f(xb[(long)c*65536 + p]);
    x1[c] = bf2f(xb[(long)c*65536 + p + 256]);
  }
  u16* hb = H + (long)b*256*65536;
  for (int o = 0; o < 256; ++o){
    const float bo = B1[o];
    float a0 = bo, a1 = bo;
    const float* wrow = &wl[o*64];
    #pragma unroll
    for (int c4 = 0; c4 < 16; ++c4){
      f4 w = *(const f4*)&wrow[c4*4];
      a0 += x0[c4*4+0]*w[0]; a0 += x0[c4*4+1]*w[1]; a0 += x0[c4*4+2]*w[2]; a0 += x0[c4*4+3]*w[3];
      a1 += x1[c4*4+0]*w[0]; a1 += x1[c4*4+1]*w[1]; a1 += x1[c4*4+2]*w[2]; a1 += x1[c4*4+3]*w[3];
    }
    hb[(long)o*65536 + p]       = f2bf(gelu_f(a0));
    hb[(long)o*65536 + p + 256] = f2bf(gelu_f(a1));
  }
}

// ---------------------------------------------------------------------------
// ff2 + residual: out[b][o2][p] = gelu(sum_o h1[b][o][p]*W2[o2][o] + b2[o2]) + feat.
// W2 staged transposed in LDS: wl[o*64+o2] = W2[o2*256+o]. 64 accumulators x 2 px.
// ---------------------------------------------------------------------------
__global__ __launch_bounds__(256,2) void ff2_k(
    const u16* __restrict__ H, const float* __restrict__ W2,
    const float* __restrict__ B2, const float* __restrict__ F, float* __restrict__ OUT)
{
  __shared__ float wl[16384];
  const int t = threadIdx.x;
  for (int i = t; i < 16384; i += 256){
    const int o = i >> 6, o2 = i & 63;
    wl[i] = W2[o2*256 + o];
  }
  __syncthreads();
  const int b = blockIdx.y;
  const long p = (long)blockIdx.x*512 + t;
  const u16* hb = H + (long)b*256*65536;
  float a0[64] = {}, a1[64] = {};
  for (int o = 0; o < 256; ++o){
    const float y0 = bf2f(hb[(long)o*65536 + p]);
    const float y1 = bf2f(hb[(long)o*65536 + p + 256]);
    const float* wrow = &wl[o*64];
    #pragma unroll
    for (int q4 = 0; q4 < 16; ++q4){
      f4 w = *(const f4*)&wrow[q4*4];
      a0[q4*4+0] += y0*w[0]; a0[q4*4+1] += y0*w[1]; a0[q4*4+2] += y0*w[2]; a0[q4*4+3] += y0*w[3];
      a1[q4*4+0] += y1*w[0]; a1[q4*4+1] += y1*w[1]; a1[q4*4+2] += y1*w[2]; a1[q4*4+3] += y1*w[3];
    }
  }
  #pragma unroll
  for (int o2 = 0; o2 < 64; ++o2){
    const long idx = ((long)(b*64 + o2))*65536 + p;
    const float bb = B2[o2];
    OUT[idx]       = gelu_f(a0[o2] + bb) + F[idx];
    OUT[idx + 256] = gelu_f(a1[o2] + bb) + F[idx + 256];
  }
}

// ---------------------------------------------------------------------------
extern "C" void kernel_launch(void* const* d_in, const int* in_sizes, int n_in,
                              void* d_out, int out_size, void* d_ws, size_t ws_size,
                              hipStream_t stream)
{
  const float* feat  = (const float*)d_in[0];
  const float* w_enc = (const float*)d_in[1];
  const float* b_enc = (const float*)d_in[2];
  const float* w_k   = (const float*)d_in[3];
  const float* b_k   = (const float*)d_in[4];
  const float* w_v   = (const float*)d_in[5];
  const float* b_v   = (const float*)d_in[6];
  const float* fcq_w = (const float*)d_in[7];
  // d_in[8] fcq_b, d_in[10] fck_b: cancelled exactly by train-mode BN mean-subtraction.
  const float* fck_w = (const float*)d_in[9];
  const float* bnq_g = (const float*)d_in[11];
  const float* bnq_b = (const float*)d_in[12];
  const float* bnk_g = (const float*)d_in[13];
  const float* bnk_b = (const float*)d_in[14];
  const float* ff1w  = (const float*)d_in[15];
  const float* ff1b  = (const float*)d_in[16];
  const float* ff2w  = (const float*)d_in[17];
  const float* ff2b  = (const float*)d_in[18];

  char* ws = (char*)d_ws;
  u16*   Aq      = (u16*)  (ws);                   // 32MB [B][1024][4096] bf16
  u16*   Ak      = (u16*)  (ws + (32ull<<20));     // 32MB
  u16*   Vc      = (u16*)  (ws + (64ull<<20));     // 32MB [B][4096][1024] bf16
  u16*   Wq      = (u16*)  (ws + (96ull<<20));     // 8MB  [1024][4096] bf16
  u16*   Wk      = (u16*)  (ws + (104ull<<20));    // 8MB
  float* q_raw   = (float*)(ws + (112ull<<20));    // 16MB [B][1024][1024]
  float* k_raw   = (float*)(ws + (128ull<<20));    // 16MB
  u16*   q_bf    = (u16*)  (ws + (144ull<<20));    // 8MB
  u16*   k_bf    = (u16*)  (ws + (152ull<<20));    // 8MB
  float* scores  = (float*)(ws + (160ull<<20));    // 16MB
  u16*   attn    = (u16*)  (ws + (176ull<<20));    // 8MB
  float* stats   = (float*)(ws + (184ull<<20));    // 32KB
  u16*   out_img = (u16*)  (ws + (185ull<<20));    // 32MB [B][64][256][256] bf16
  u16*   h1      = (u16*)  (ws);                   // 128MB reuse [0,128MB): Aq..k_bf dead by ff1
  float* sum_q = stats,        *sumsq_q = stats+1024;
  float* sum_k = stats+2048,   *sumsq_k = stats+3072;
  float* scale_q = stats+4096, *shift_q = stats+5120;
  float* scale_k = stats+6144, *shift_k = stats+7168;

  hipMemsetAsync(stats, 0, 4096*sizeof(float), stream);   // zero the 4 sum arrays

  conv3_fused<<<dim3(32,64,4), 256, 0, stream>>>(feat, w_enc, w_k, w_v,
                                                 b_enc, b_k, b_v, Aq, Ak, Vc);
  cvt_w<<<dim3(4096,2), 256, 0, stream>>>(fcq_w, fck_w, Wq, Wk);

  // projections: q_raw[b] = Aq[b] (1024x4096) * Wq^T  (bias dropped; BN cancels it)
  gemm_bt<0><<<dim3(8,8,4),  256, 0, stream>>>(Aq, 4194304, Wq, 0, q_raw, 1048576, 1024, 1024, 4096);
  gemm_bt<0><<<dim3(8,8,4),  256, 0, stream>>>(Ak, 4194304, Wk, 0, k_raw, 1048576, 1024, 1024, 4096);

  bn_stats<<<dim3(256), 256, 0, stream>>>(q_raw, sum_q, sumsq_q);
  bn_stats<<<dim3(256), 256, 0, stream>>>(k_raw, sum_k, sumsq_k);
  bn_fin<<<dim3(4), 256, 0, stream>>>(sum_q, sumsq_q, bnq_g, bnq_b, scale_q, shift_q);
  bn_fin<<<dim3(4), 256, 0, stream>>>(sum_k, sumsq_k, bnk_g, bnk_b, scale_k, shift_k);
  bn_apply<<<dim3(4096), 256, 0, stream>>>(q_raw, scale_q, shift_q, q_bf);
  bn_apply<<<dim3(4096), 256, 0, stream>>>(k_raw, scale_k, shift_k, k_bf);

  // scores[b] = q_bf[b] * k_bf[b]^T   (scale 1/32 applied in softmax)
  gemm_bt<0><<<dim3(8,8,4),  256, 0, stream>>>(q_bf, 1048576, k_bf, 1048576, scores, 1048576, 1024, 1024, 1024);
  softmax_k<<<dim3(4096), 256, 0, stream>>>(scores, attn);

  // out[b] = attn[b] * Vc[b]^T, epilogue folds to NCHW bf16
  gemm_bt<1><<<dim3(8,32,4), 256, 0, stream>>>(attn, 1048576, Vc, 4194304, out_img, 0, 1024, 4096, 1024);

  ff1_k<<<dim3(128,4), 256, 0, stream>>>(out_img, ff1w, ff1b, h1);
  ff2_k<<<dim3(128,4), 256, 0, stream>>>(h1, ff2w, ff2b, feat, (float*)d_out);
}

// Round 2
// 940.093 us; speedup vs baseline: 1.8669x; 1.8669x over previous
//
#include <hip/hip_runtime.h>

typedef unsigned short u16;
typedef float f4 __attribute__((ext_vector_type(4)));
typedef float f32x4 __attribute__((ext_vector_type(4)));
typedef short bf16x8 __attribute__((ext_vector_type(8)));
typedef u16 u16x8 __attribute__((ext_vector_type(8)));
typedef u16 u16x4 __attribute__((ext_vector_type(4)));

__device__ __forceinline__ u16 f2bf(float f){
  unsigned u = __float_as_uint(f);
  u = (u + 0x7FFFu + ((u>>16)&1u)) >> 16;
  return (u16)u;
}
__device__ __forceinline__ float bf2f(u16 u){
  return __uint_as_float(((unsigned)u)<<16);
}
__device__ __forceinline__ float gelu_f(float x){
  return 0.5f*x*(1.0f+erff(x*0.70710678118654752440f));
}

// ---------------------------------------------------------------------------
// feat NCHW fp32 -> NHWC bf16  ([4][256][256][64])
// block: 64 px x 64 ch tile via LDS.
// ---------------------------------------------------------------------------
__global__ __launch_bounds__(256) void to_nhwc(
    const float* __restrict__ F, u16* __restrict__ O)
{
  __shared__ float tile[64][65];
  const int t = threadIdx.x, b = blockIdx.y;
  const long px0 = (long)blockIdx.x*64;
  const float* Fb = F + (long)b*64*65536;
  #pragma unroll
  for (int i = 0; i < 4; ++i){
    const int ch = (t>>4) + i*16;
    const int pxo = (t&15)*4;
    f4 v = *(const f4*)&Fb[(long)ch*65536 + px0 + pxo];
    tile[ch][pxo]=v[0]; tile[ch][pxo+1]=v[1]; tile[ch][pxo+2]=v[2]; tile[ch][pxo+3]=v[3];
  }
  __syncthreads();
  const int px = t & 63, ch0 = (t>>6)*16;
  u16x8 o0, o1;
  #pragma unroll
  for (int j = 0; j < 8; ++j){ o0[j]=f2bf(tile[ch0+j][px]); o1[j]=f2bf(tile[ch0+8+j][px]); }
  u16* Ob = O + ((long)b*65536 + px0 + px)*64 + ch0;
  *(u16x8*)Ob = o0; *(u16x8*)(Ob+8) = o1;
}

// ---------------------------------------------------------------------------
// conv weights [co][ci][3][3] f32 x3 -> Wt [n=192][dy][dx][ci=64] bf16
// ---------------------------------------------------------------------------
__global__ __launch_bounds__(256) void wt_prep(
    const float* __restrict__ we, const float* __restrict__ wk,
    const float* __restrict__ wv, u16* __restrict__ Wt)
{
  const int i = blockIdx.x*256 + threadIdx.x;   // 110592 total
  const int n = i / 576, r = i % 576;
  const int dy = r / 192, r2 = r % 192, dx = r2 / 64, ci = r2 % 64;
  const float* W = (n < 64) ? we : (n < 128) ? wk : wv;
  const int co = n & 63;
  Wt[i] = f2bf(W[((co*64 + ci)*3 + dy)*3 + dx]);
}

// ---------------------------------------------------------------------------
// MFMA implicit-GEMM conv: 3 convs fused (N=192), shifted-window formulation.
// Block: 8x16 px tile x 192 couts; halo 10x18x64 bf16 staged once (XOR-swizzled
// 16B chunks); per-(dy,dx) weight panel [192][64] staged to LDS; K = 9*64.
// Epilogue: bias+GELU+bf16, writes Aq/Ak ([b][l][4096]) and Vl ([b][l][4096]).
// ---------------------------------------------------------------------------
__global__ __launch_bounds__(256,2) void conv_mfma(
    const u16* __restrict__ X, const u16* __restrict__ Wt,
    const float* __restrict__ be, const float* __restrict__ bk, const float* __restrict__ bv,
    u16* __restrict__ Aq, u16* __restrict__ Ak, u16* __restrict__ Vl)
{
  __shared__ __align__(16) u16 halo[10*18*64];   // 23040 B
  __shared__ __align__(16) u16 wlds[192*64];     // 24576 B
  const int t = threadIdx.x, lane = t & 63, wvi = t >> 6;
  const int bx = blockIdx.x, by = blockIdx.y, b = blockIdx.z;
  const int x0 = bx*16, y0 = by*8;
  const u16* Xb = X + (long)b*4194304;

  // ---- stage halo (once per block) ----
  #pragma unroll
  for (int j = 0; j < 6; ++j){
    const int id = t + j*256;
    if (id < 1440){
      const int row = id / 144, rem = id - row*144, col = rem >> 3, ck = rem & 7;
      const int y = y0 - 1 + row, x = x0 - 1 + col;
      int4 v = {0,0,0,0};
      if ((unsigned)y < 256u && (unsigned)x < 256u)
        v = *(const int4*)(Xb + ((long)y*256 + x)*64 + ck*8);
      *(int4*)&halo[((row*18 + col)*8 + (ck ^ (col&7)))*8] = v;
    }
  }

  const int wm4 = (wvi>>1)*4;          // pixel-row base (r = wm4+mi)
  const int wn  = (wvi&1)*96;          // cout base
  const int fr = lane & 15, fo = lane >> 4;
  f32x4 acc[4][6] = {};

  for (int dy = 0; dy < 3; ++dy)
  for (int dx = 0; dx < 3; ++dx){
    __syncthreads();                   // protect wlds reuse
    #pragma unroll
    for (int j = 0; j < 6; ++j){
      const int id = t + j*256;        // 1536 chunks
      const int n = id >> 3, ck = id & 7;
      int4 v = *(const int4*)(Wt + ((long)n*9 + dy*3 + dx)*64 + ck*8);
      *(int4*)&wlds[(n*8 + (ck ^ (n&7)))*8] = v;
    }
    __syncthreads();
    #pragma unroll
    for (int kc = 0; kc < 2; ++kc){
      bf16x8 af[4], bfv[6];
      #pragma unroll
      for (int mi = 0; mi < 4; ++mi){
        const int row = wm4 + mi + dy;           // 0..9
        const int col = fr + dx;                 // 0..17
        af[mi] = *(const bf16x8*)&halo[((row*18 + col)*8 + ((kc*4+fo) ^ (col&7)))*8];
      }
      #pragma unroll
      for (int ni = 0; ni < 6; ++ni){
        const int n = wn + ni*16 + fr;
        bfv[ni] = *(const bf16x8*)&wlds[(n*8 + ((kc*4+fo) ^ (n&7)))*8];
      }
      #pragma unroll
      for (int mi = 0; mi < 4; ++mi)
        #pragma unroll
        for (int ni = 0; ni < 6; ++ni)
          acc[mi][ni] = __builtin_amdgcn_mfma_f32_16x16x32_bf16(af[mi], bfv[ni], acc[mi][ni], 0, 0, 0);
    }
  }

  // ---- epilogue: bias + GELU + bf16, unfolded layouts ----
  // C frag: row(m) = fo*4+rg -> pixel (r = wm4+mi, c = fo*4+rg); col(n) = fr.
  const int c0 = fo*4;
  const int l  = by*32 + bx*2 + (c0>>3);
  const int kw0 = c0 & 7;
  #pragma unroll
  for (int ni = 0; ni < 6; ++ni){
    const int n = wn + ni*16 + fr;
    const int g = n >> 6, co = n & 63;
    const float bias = (g==0) ? be[co] : (g==1) ? bk[co] : bv[co];
    #pragma unroll
    for (int mi = 0; mi < 4; ++mi){
      const int r = wm4 + mi;                    // kh
      u16x4 o;
      #pragma unroll
      for (int rg = 0; rg < 4; ++rg) o[rg] = f2bf(gelu_f(acc[mi][ni][rg] + bias));
      const long base = ((long)b*1024 + l)*4096 + co*64 + r*8 + kw0;
      if (g == 0)      *(u16x4*)(Aq + base) = o;
      else if (g == 1) *(u16x4*)(Ak + base) = o;
      else             *(u16x4*)(Vl + base) = o;
    }
  }
}

// ---------------------------------------------------------------------------
// V transpose: [b][l=1024][ck=4096] -> [b][ck][l]  (bf16, 64x64 LDS tiles)
// ---------------------------------------------------------------------------
__global__ __launch_bounds__(256) void v_tr(
    const u16* __restrict__ S, u16* __restrict__ D)
{
  __shared__ u16 tl[64][72];
  const int t = threadIdx.x, b = blockIdx.z;
  const int ck0 = blockIdx.x*64, l0 = blockIdx.y*64;
  const u16* Sb = S + (long)b*4194304;
  u16* Db = D + (long)b*4194304;
  #pragma unroll
  for (int j = 0; j < 2; ++j){
    const int li = (t>>3) + j*32, cko = (t&7)*8;
    *(u16x8*)&tl[li][cko] = *(const u16x8*)(Sb + (long)(l0+li)*4096 + ck0 + cko);
  }
  __syncthreads();
  #pragma unroll
  for (int j = 0; j < 2; ++j){
    const int cki = (t>>3) + j*32, lo = (t&7)*8;
    u16x8 v;
    #pragma unroll
    for (int e = 0; e < 8; ++e) v[e] = tl[lo+e][cki];
    *(u16x8*)(Db + (long)(ck0+cki)*1024 + l0 + lo) = v;
  }
}

// ---------------------------------------------------------------------------
// bf16 MFMA GEMM: C[b] = A[b] (MxK) * B[b]^T (B stored [N][K]). 128x128 tile.
// ---------------------------------------------------------------------------
template<int EPI>
__global__ __launch_bounds__(256,2) void gemm_bt(
    const u16* __restrict__ A, long sA,
    const u16* __restrict__ B, long sB,
    void* __restrict__ Cv, long sC,
    const int M, const int N, const int K)
{
  const int bI = blockIdx.z;
  const u16* Ab = A + (long)bI*sA;
  const u16* Bb = B + (long)bI*sB;
  const int m0 = blockIdx.x*128, n0 = blockIdx.y*128;
  __shared__ __align__(16) u16 As[128][40];
  __shared__ __align__(16) u16 Bs[128][40];
  const int t = threadIdx.x, lane = t & 63, wv = t >> 6;
  const int wm = (wv>>1)*64, wn = (wv&1)*64;
  const int fr = lane & 15, fo = lane >> 4;
  f32x4 acc[4][4] = {};
  const int c0 = t*2, c1 = t*2+1;
  const int r0_ = c0>>2, k0_ = (c0&3)*8, r1_ = c1>>2, k1_ = (c1&3)*8;
  const u16* Ag0 = Ab + (long)(m0+r0_)*K + k0_;
  const u16* Ag1 = Ab + (long)(m0+r1_)*K + k1_;
  const u16* Bg0 = Bb + (long)(n0+r0_)*K + k0_;
  const u16* Bg1 = Bb + (long)(n0+r1_)*K + k1_;
  for (int k0 = 0; k0 < K; k0 += 32){
    __syncthreads();
    *(int4*)&As[r0_][k0_] = *(const int4*)(Ag0 + k0);
    *(int4*)&As[r1_][k1_] = *(const int4*)(Ag1 + k0);
    *(int4*)&Bs[r0_][k0_] = *(const int4*)(Bg0 + k0);
    *(int4*)&Bs[r1_][k1_] = *(const int4*)(Bg1 + k0);
    __syncthreads();
    bf16x8 af[4], bfv[4];
    #pragma unroll
    for (int i = 0; i < 4; ++i){
      af[i]  = *(const bf16x8*)&As[wm + i*16 + fr][fo*8];
      bfv[i] = *(const bf16x8*)&Bs[wn + i*16 + fr][fo*8];
    }
    #pragma unroll
    for (int mi = 0; mi < 4; ++mi)
      #pragma unroll
      for (int ni = 0; ni < 4; ++ni)
        acc[mi][ni] = __builtin_amdgcn_mfma_f32_16x16x32_bf16(af[mi], bfv[ni], acc[mi][ni], 0, 0, 0);
  }
  if (EPI == 0){
    float* Cf = (float*)Cv + (long)bI*sC;
    #pragma unroll
    for (int mi = 0; mi < 4; ++mi)
      #pragma unroll
      for (int ni = 0; ni < 4; ++ni){
        const int col = n0 + wn + ni*16 + fr;
        #pragma unroll
        for (int r = 0; r < 4; ++r){
          const int row = m0 + wm + mi*16 + fo*4 + r;
          Cf[(long)row*N + col] = acc[mi][ni][r];
        }
      }
  } else {
    u16* O = (u16*)Cv;
    #pragma unroll
    for (int mi = 0; mi < 4; ++mi)
      #pragma unroll
      for (int ni = 0; ni < 4; ++ni){
        const int col = n0 + wn + ni*16 + fr;
        const int c = col >> 6, khh = (col>>3)&7, kww = col&7;
        #pragma unroll
        for (int r = 0; r < 4; ++r){
          const int row = m0 + wm + mi*16 + fo*4 + r;
          const int hb = row >> 5, wbb = row & 31;
          O[(((long)(bI*64 + c)*256 + hb*8 + khh)*256) + wbb*8 + kww] = f2bf(acc[mi][ni][r]);
        }
      }
  }
}

// ---------------------------------------------------------------------------
__global__ __launch_bounds__(256) void cvt_w(
    const float* __restrict__ Wq, const float* __restrict__ Wk,
    u16* __restrict__ Oq, u16* __restrict__ Ok)
{
  const long i = ((long)blockIdx.x*256 + threadIdx.x)*4;
  const float* s = blockIdx.y ? Wk : Wq;
  u16* d = blockIdx.y ? Ok : Oq;
  f4 v = *(const f4*)&s[i];
  u16x4 o; o[0]=f2bf(v[0]); o[1]=f2bf(v[1]); o[2]=f2bf(v[2]); o[3]=f2bf(v[3]);
  *(u16x4*)&d[i] = o;
}

__global__ __launch_bounds__(256) void bn_stats(
    const float* __restrict__ X, float* __restrict__ sum, float* __restrict__ sumsq)
{
  const int t = threadIdx.x;
  const long r0 = (long)blockIdx.x*16;
  f4 s = {0,0,0,0}, q = {0,0,0,0};
  for (int r = 0; r < 16; ++r){
    f4 v = *(const f4*)&X[(r0 + r)*1024 + t*4];
    s += v; q += v*v;
  }
  atomicAdd(&sum[t*4+0], s[0]); atomicAdd(&sum[t*4+1], s[1]);
  atomicAdd(&sum[t*4+2], s[2]); atomicAdd(&sum[t*4+3], s[3]);
  atomicAdd(&sumsq[t*4+0], q[0]); atomicAdd(&sumsq[t*4+1], q[1]);
  atomicAdd(&sumsq[t*4+2], q[2]); atomicAdd(&sumsq[t*4+3], q[3]);
}

__global__ void bn_fin(const float* __restrict__ sum, const float* __restrict__ sumsq,
                       const float* __restrict__ g, const float* __restrict__ beta,
                       float* __restrict__ scale, float* __restrict__ shift)
{
  const int d = blockIdx.x*256 + threadIdx.x;
  if (d >= 1024) return;
  const float m  = sum[d]   * (1.f/4096.f);
  const float vv = sumsq[d] * (1.f/4096.f) - m*m;
  const float sc = g[d] * rsqrtf(vv + 1e-5f);
  scale[d] = sc;
  shift[d] = beta[d] - m*sc;
}

__global__ __launch_bounds__(256) void bn_apply(
    const float* __restrict__ X, const float* __restrict__ scale,
    const float* __restrict__ shift, u16* __restrict__ Y)
{
  const long i = ((long)blockIdx.x*256 + threadIdx.x)*4;
  f4 v = *(const f4*)&X[i];
  const int d = (int)(i & 1023);
  const f4 sc = *(const f4*)&scale[d];
  const f4 sh = *(const f4*)&shift[d];
  v = v*sc + sh;
  u16x4 o; o[0]=f2bf(v[0]); o[1]=f2bf(v[1]); o[2]=f2bf(v[2]); o[3]=f2bf(v[3]);
  *(u16x4*)&Y[i] = o;
}

__global__ __launch_bounds__(256) void softmax_k(
    const float* __restrict__ S, u16* __restrict__ P)
{
  const long row = blockIdx.x;
  const float* p = S + row*1024;
  const int t = threadIdx.x;
  f4 v = *(const f4*)&p[t*4];
  v *= 0.03125f;
  float mx = fmaxf(fmaxf(v[0],v[1]), fmaxf(v[2],v[3]));
  #pragma unroll
  for (int o = 1; o < 64; o <<= 1) mx = fmaxf(mx, __shfl_xor(mx, o));
  __shared__ float red[4], red2[4];
  if ((t & 63) == 0) red[t>>6] = mx;
  __syncthreads();
  mx = fmaxf(fmaxf(red[0],red[1]), fmaxf(red[2],red[3]));
  f4 e;
  e[0]=__expf(v[0]-mx); e[1]=__expf(v[1]-mx); e[2]=__expf(v[2]-mx); e[3]=__expf(v[3]-mx);
  float sm = e[0]+e[1]+e[2]+e[3];
  #pragma unroll
  for (int o = 1; o < 64; o <<= 1) sm += __shfl_xor(sm, o);
  if ((t & 63) == 0) red2[t>>6] = sm;
  __syncthreads();
  sm = red2[0]+red2[1]+red2[2]+red2[3];
  const float inv = 1.0f/sm;
  u16x4 o4; o4[0]=f2bf(e[0]*inv); o4[1]=f2bf(e[1]*inv); o4[2]=f2bf(e[2]*inv); o4[3]=f2bf(e[3]*inv);
  *(u16x4*)&P[row*1024 + t*4] = o4;
}

__global__ __launch_bounds__(256,2) void ff1_k(
    const u16* __restrict__ X, const float* __restrict__ W1,
    const float* __restrict__ B1, u16* __restrict__ H)
{
  __shared__ float wl[16384];
  const int t = threadIdx.x;
  for (int i = t; i < 16384; i += 256) wl[i] = W1[i];
  __syncthreads();
  const int b = blockIdx.y;
  const long p = (long)blockIdx.x*512 + t;
  const u16* xb = X + (long)b*64*65536;
  float x0[64], x1[64];
  #pragma unroll
  for (int c = 0; c < 64; ++c){
    x0[c] = bf2f(xb[(long)c*65536 + p]);
    x1[c] = bf2f(xb[(long)c*65536 + p + 256]);
  }
  u16* hb = H + (long)b*256*65536;
  for (int o = 0; o < 256; ++o){
    const float bo = B1[o];
    float a0 = bo, a1 = bo;
    const float* wrow = &wl[o*64];
    #pragma unroll
    for (int c4 = 0; c4 < 16; ++c4){
      f4 w = *(const f4*)&wrow[c4*4];
      a0 += x0[c4*4+0]*w[0]; a0 += x0[c4*4+1]*w[1]; a0 += x0[c4*4+2]*w[2]; a0 += x0[c4*4+3]*w[3];
      a1 += x1[c4*4+0]*w[0]; a1 += x1[c4*4+1]*w[1]; a1 += x1[c4*4+2]*w[2]; a1 += x1[c4*4+3]*w[3];
    }
    hb[(long)o*65536 + p]       = f2bf(gelu_f(a0));
    hb[(long)o*65536 + p + 256] = f2bf(gelu_f(a1));
  }
}

__global__ __launch_bounds__(256,2) void ff2_k(
    const u16* __restrict__ H, const float* __restrict__ W2,
    const float* __restrict__ B2, const float* __restrict__ F, float* __restrict__ OUT)
{
  __shared__ float wl[16384];
  const int t = threadIdx.x;
  for (int i = t; i < 16384; i += 256){
    const int o = i >> 6, o2 = i & 63;
    wl[i] = W2[o2*256 + o];
  }
  __syncthreads();
  const int b = blockIdx.y;
  const long p = (long)blockIdx.x*512 + t;
  const u16* hb = H + (long)b*256*65536;
  float a0[64] = {}, a1[64] = {};
  for (int o = 0; o < 256; ++o){
    const float y0 = bf2f(hb[(long)o*65536 + p]);
    const float y1 = bf2f(hb[(long)o*65536 + p + 256]);
    const float* wrow = &wl[o*64];
    #pragma unroll
    for (int q4 = 0; q4 < 16; ++q4){
      f4 w = *(const f4*)&wrow[q4*4];
      a0[q4*4+0] += y0*w[0]; a0[q4*4+1] += y0*w[1]; a0[q4*4+2] += y0*w[2]; a0[q4*4+3] += y0*w[3];
      a1[q4*4+0] += y1*w[0]; a1[q4*4+1] += y1*w[1]; a1[q4*4+2] += y1*w[2]; a1[q4*4+3] += y1*w[3];
    }
  }
  #pragma unroll
  for (int o2 = 0; o2 < 64; ++o2){
    const long idx = ((long)(b*64 + o2))*65536 + p;
    const float bb = B2[o2];
    OUT[idx]       = gelu_f(a0[o2] + bb) + F[idx];
    OUT[idx + 256] = gelu_f(a1[o2] + bb) + F[idx + 256];
  }
}

// ---------------------------------------------------------------------------
extern "C" void kernel_launch(void* const* d_in, const int* in_sizes, int n_in,
                              void* d_out, int out_size, void* d_ws, size_t ws_size,
                              hipStream_t stream)
{
  const float* feat  = (const float*)d_in[0];
  const float* w_enc = (const float*)d_in[1];
  const float* b_enc = (const float*)d_in[2];
  const float* w_k   = (const float*)d_in[3];
  const float* b_k   = (const float*)d_in[4];
  const float* w_v   = (const float*)d_in[5];
  const float* b_v   = (const float*)d_in[6];
  const float* fcq_w = (const float*)d_in[7];
  // d_in[8] fcq_b, d_in[10] fck_b: cancelled exactly by train-mode BN.
  const float* fck_w = (const float*)d_in[9];
  const float* bnq_g = (const float*)d_in[11];
  const float* bnq_b = (const float*)d_in[12];
  const float* bnk_g = (const float*)d_in[13];
  const float* bnk_b = (const float*)d_in[14];
  const float* ff1w  = (const float*)d_in[15];
  const float* ff1b  = (const float*)d_in[16];
  const float* ff2w  = (const float*)d_in[17];
  const float* ff2b  = (const float*)d_in[18];

  char* ws = (char*)d_ws;
  u16*   Aq      = (u16*)  (ws);                   // [0,32)  MB [B][L][4096]
  u16*   Ak      = (u16*)  (ws + (32ull<<20));     // [32,64)
  u16*   Vc      = (u16*)  (ws + (64ull<<20));     // [64,96)  [B][4096][L]
  u16*   Wq      = (u16*)  (ws + (96ull<<20));     // [96,104)
  u16*   Wk      = (u16*)  (ws + (104ull<<20));    // [104,112)
  u16*   q_bf    = (u16*)  (ws + (112ull<<20));    // [112,120)
  u16*   k_bf    = (u16*)  (ws + (120ull<<20));    // [120,128)
  float* q_raw   = (float*)(ws + (128ull<<20));    // [128,144)
  float* k_raw   = (float*)(ws + (144ull<<20));    // [144,160)
  float* scores  = (float*)(ws + (160ull<<20));    // [160,176)
  u16*   attn    = (u16*)  (ws + (176ull<<20));    // [176,184)
  u16*   out_img = (u16*)  (ws + (184ull<<20));    // [184,216) [B][64][256][256]
  u16*   NX      = (u16*)  (ws + (128ull<<20));    // [128,160) transient (dead before q_raw/k_raw)
  u16*   Vl      = (u16*)  (ws + (160ull<<20));    // [160,192) transient (dead before scores/attn/out_img)
  u16*   Wt      = (u16*)  (ws + (216ull<<20));    // [216, +221KB)
  float* stats   = (float*)(ws + (217ull<<20));    // 32KB
  u16*   h1      = (u16*)  (ws);                   // [0,128) reuse: Aq..k_bf dead by ff1
  float* sum_q = stats,        *sumsq_q = stats+1024;
  float* sum_k = stats+2048,   *sumsq_k = stats+3072;
  float* scale_q = stats+4096, *shift_q = stats+5120;
  float* scale_k = stats+6144, *shift_k = stats+7168;

  hipMemsetAsync(stats, 0, 4096*sizeof(float), stream);

  to_nhwc<<<dim3(1024,4), 256, 0, stream>>>(feat, NX);
  wt_prep<<<dim3(432), 256, 0, stream>>>(w_enc, w_k, w_v, Wt);
  conv_mfma<<<dim3(16,32,4), 256, 0, stream>>>(NX, Wt, b_enc, b_k, b_v, Aq, Ak, Vl);
  v_tr<<<dim3(64,16,4), 256, 0, stream>>>(Vl, Vc);
  cvt_w<<<dim3(4096,2), 256, 0, stream>>>(fcq_w, fck_w, Wq, Wk);

  gemm_bt<0><<<dim3(8,8,4),  256, 0, stream>>>(Aq, 4194304, Wq, 0, q_raw, 1048576, 1024, 1024, 4096);
  gemm_bt<0><<<dim3(8,8,4),  256, 0, stream>>>(Ak, 4194304, Wk, 0, k_raw, 1048576, 1024, 1024, 4096);

  bn_stats<<<dim3(256), 256, 0, stream>>>(q_raw, sum_q, sumsq_q);
  bn_stats<<<dim3(256), 256, 0, stream>>>(k_raw, sum_k, sumsq_k);
  bn_fin<<<dim3(4), 256, 0, stream>>>(sum_q, sumsq_q, bnq_g, bnq_b, scale_q, shift_q);
  bn_fin<<<dim3(4), 256, 0, stream>>>(sum_k, sumsq_k, bnk_g, bnk_b, scale_k, shift_k);
  bn_apply<<<dim3(4096), 256, 0, stream>>>(q_raw, scale_q, shift_q, q_bf);
  bn_apply<<<dim3(4096), 256, 0, stream>>>(k_raw, scale_k, shift_k, k_bf);

  gemm_bt<0><<<dim3(8,8,4),  256, 0, stream>>>(q_bf, 1048576, k_bf, 1048576, scores, 1048576, 1024, 1024, 1024);
  softmax_k<<<dim3(4096), 256, 0, stream>>>(scores, attn);

  gemm_bt<1><<<dim3(8,32,4), 256, 0, stream>>>(attn, 1048576, Vc, 4194304, out_img, 0, 1024, 4096, 1024);

  ff1_k<<<dim3(128,4), 256, 0, stream>>>(out_img, ff1w, ff1b, h1);
  ff2_k<<<dim3(128,4), 256, 0, stream>>>(h1, ff2w, ff2b, feat, (float*)d_out);
}

// Round 4
// 848.998 us; speedup vs baseline: 2.0672x; 1.1073x over previous
//
#include <hip/hip_runtime.h>

typedef unsigned short u16;
typedef float f4 __attribute__((ext_vector_type(4)));
typedef float f32x4 __attribute__((ext_vector_type(4)));
typedef short bf16x8 __attribute__((ext_vector_type(8)));
typedef u16 u16x8 __attribute__((ext_vector_type(8)));
typedef u16 u16x4 __attribute__((ext_vector_type(4)));

__device__ __forceinline__ u16 f2bf(float f){
  unsigned u = __float_as_uint(f);
  u = (u + 0x7FFFu + ((u>>16)&1u)) >> 16;
  return (u16)u;
}
__device__ __forceinline__ float bf2f(u16 u){
  return __uint_as_float(((unsigned)u)<<16);
}
__device__ __forceinline__ float gelu_f(float x){
  return 0.5f*x*(1.0f+erff(x*0.70710678118654752440f));
}

// ---------------------------------------------------------------------------
// feat NCHW fp32 -> NHWC bf16  ([4][256][256][64])
// ---------------------------------------------------------------------------
__global__ __launch_bounds__(256) void to_nhwc(
    const float* __restrict__ F, u16* __restrict__ O)
{
  __shared__ float tile[64][65];
  const int t = threadIdx.x, b = blockIdx.y;
  const long px0 = (long)blockIdx.x*64;
  const float* Fb = F + (long)b*64*65536;
  #pragma unroll
  for (int i = 0; i < 4; ++i){
    const int ch = (t>>4) + i*16;
    const int pxo = (t&15)*4;
    f4 v = *(const f4*)&Fb[(long)ch*65536 + px0 + pxo];
    tile[ch][pxo]=v[0]; tile[ch][pxo+1]=v[1]; tile[ch][pxo+2]=v[2]; tile[ch][pxo+3]=v[3];
  }
  __syncthreads();
  const int px = t & 63, ch0 = (t>>6)*16;
  u16x8 o0, o1;
  #pragma unroll
  for (int j = 0; j < 8; ++j){ o0[j]=f2bf(tile[ch0+j][px]); o1[j]=f2bf(tile[ch0+8+j][px]); }
  u16* Ob = O + ((long)b*65536 + px0 + px)*64 + ch0;
  *(u16x8*)Ob = o0; *(u16x8*)(Ob+8) = o1;
}

// ---------------------------------------------------------------------------
// conv weights [co][ci][3][3] f32 x3 -> Wt [n=192][dy][dx][ci=64] bf16
// ---------------------------------------------------------------------------
__global__ __launch_bounds__(256) void wt_prep(
    const float* __restrict__ we, const float* __restrict__ wk,
    const float* __restrict__ wv, u16* __restrict__ Wt)
{
  const int i = blockIdx.x*256 + threadIdx.x;   // 110592 total
  const int n = i / 576, r = i % 576;
  const int dy = r / 192, r2 = r % 192, dx = r2 / 64, ci = r2 % 64;
  const float* W = (n < 64) ? we : (n < 128) ? wk : wv;
  const int co = n & 63;
  Wt[i] = f2bf(W[((co*64 + ci)*3 + dy)*3 + dx]);
}

// ---------------------------------------------------------------------------
// MFMA implicit-GEMM conv (3 convs fused, N=192). See round-2 comments.
// ---------------------------------------------------------------------------
__global__ __launch_bounds__(256,2) void conv_mfma(
    const u16* __restrict__ X, const u16* __restrict__ Wt,
    const float* __restrict__ be, const float* __restrict__ bk, const float* __restrict__ bv,
    u16* __restrict__ Aq, u16* __restrict__ Ak, u16* __restrict__ Vl)
{
  __shared__ __align__(16) u16 halo[10*18*64];
  __shared__ __align__(16) u16 wlds[192*64];
  const int t = threadIdx.x, lane = t & 63, wvi = t >> 6;
  const int bx = blockIdx.x, by = blockIdx.y, b = blockIdx.z;
  const int x0 = bx*16, y0 = by*8;
  const u16* Xb = X + (long)b*4194304;

  #pragma unroll
  for (int j = 0; j < 6; ++j){
    const int id = t + j*256;
    if (id < 1440){
      const int row = id / 144, rem = id - row*144, col = rem >> 3, ck = rem & 7;
      const int y = y0 - 1 + row, x = x0 - 1 + col;
      int4 v = {0,0,0,0};
      if ((unsigned)y < 256u && (unsigned)x < 256u)
        v = *(const int4*)(Xb + ((long)y*256 + x)*64 + ck*8);
      *(int4*)&halo[((row*18 + col)*8 + (ck ^ (col&7)))*8] = v;
    }
  }

  const int wm4 = (wvi>>1)*4;
  const int wn  = (wvi&1)*96;
  const int fr = lane & 15, fo = lane >> 4;
  f32x4 acc[4][6] = {};

  for (int dy = 0; dy < 3; ++dy)
  for (int dx = 0; dx < 3; ++dx){
    __syncthreads();
    #pragma unroll
    for (int j = 0; j < 6; ++j){
      const int id = t + j*256;
      const int n = id >> 3, ck = id & 7;
      int4 v = *(const int4*)(Wt + ((long)n*9 + dy*3 + dx)*64 + ck*8);
      *(int4*)&wlds[(n*8 + (ck ^ (n&7)))*8] = v;
    }
    __syncthreads();
    #pragma unroll
    for (int kc = 0; kc < 2; ++kc){
      bf16x8 af[4], bfv[6];
      #pragma unroll
      for (int mi = 0; mi < 4; ++mi){
        const int row = wm4 + mi + dy;
        const int col = fr + dx;
        af[mi] = *(const bf16x8*)&halo[((row*18 + col)*8 + ((kc*4+fo) ^ (col&7)))*8];
      }
      #pragma unroll
      for (int ni = 0; ni < 6; ++ni){
        const int n = wn + ni*16 + fr;
        bfv[ni] = *(const bf16x8*)&wlds[(n*8 + ((kc*4+fo) ^ (n&7)))*8];
      }
      #pragma unroll
      for (int mi = 0; mi < 4; ++mi)
        #pragma unroll
        for (int ni = 0; ni < 6; ++ni)
          acc[mi][ni] = __builtin_amdgcn_mfma_f32_16x16x32_bf16(af[mi], bfv[ni], acc[mi][ni], 0, 0, 0);
    }
  }

  const int c0 = fo*4;
  const int l  = by*32 + bx*2 + (c0>>3);
  const int kw0 = c0 & 7;
  #pragma unroll
  for (int ni = 0; ni < 6; ++ni){
    const int n = wn + ni*16 + fr;
    const int g = n >> 6, co = n & 63;
    const float bias = (g==0) ? be[co] : (g==1) ? bk[co] : bv[co];
    #pragma unroll
    for (int mi = 0; mi < 4; ++mi){
      const int r = wm4 + mi;
      u16x4 o;
      #pragma unroll
      for (int rg = 0; rg < 4; ++rg) o[rg] = f2bf(gelu_f(acc[mi][ni][rg] + bias));
      const long base = ((long)b*1024 + l)*4096 + co*64 + r*8 + kw0;
      if (g == 0)      *(u16x4*)(Aq + base) = o;
      else if (g == 1) *(u16x4*)(Ak + base) = o;
      else             *(u16x4*)(Vl + base) = o;
    }
  }
}

// ---------------------------------------------------------------------------
// V transpose: [b][l=1024][ck=4096] -> [b][ck][l]
// ---------------------------------------------------------------------------
__global__ __launch_bounds__(256) void v_tr(
    const u16* __restrict__ S, u16* __restrict__ D)
{
  __shared__ u16 tl[64][72];
  const int t = threadIdx.x, b = blockIdx.z;
  const int ck0 = blockIdx.x*64, l0 = blockIdx.y*64;
  const u16* Sb = S + (long)b*4194304;
  u16* Db = D + (long)b*4194304;
  #pragma unroll
  for (int j = 0; j < 2; ++j){
    const int li = (t>>3) + j*32, cko = (t&7)*8;
    *(u16x8*)&tl[li][cko] = *(const u16x8*)(Sb + (long)(l0+li)*4096 + ck0 + cko);
  }
  __syncthreads();
  #pragma unroll
  for (int j = 0; j < 2; ++j){
    const int cki = (t>>3) + j*32, lo = (t&7)*8;
    u16x8 v;
    #pragma unroll
    for (int e = 0; e < 8; ++e) v[e] = tl[lo+e][cki];
    *(u16x8*)(Db + (long)(ck0+cki)*1024 + l0 + lo) = v;
  }
}

// ---------------------------------------------------------------------------
// bf16 MFMA GEMM: C[b] = A[b] (MxK) * B[b]^T. EPI 0: fp32 C. EPI 1: NHWC fold.
// ---------------------------------------------------------------------------
template<int EPI>
__global__ __launch_bounds__(256,2) void gemm_bt(
    const u16* __restrict__ A, long sA,
    const u16* __restrict__ B, long sB,
    void* __restrict__ Cv, long sC,
    const int M, const int N, const int K)
{
  const int bI = blockIdx.z;
  const u16* Ab = A + (long)bI*sA;
  const u16* Bb = B + (long)bI*sB;
  const int m0 = blockIdx.x*128, n0 = blockIdx.y*128;
  __shared__ __align__(16) u16 As[128][40];
  __shared__ __align__(16) u16 Bs[128][40];
  const int t = threadIdx.x, lane = t & 63, wv = t >> 6;
  const int wm = (wv>>1)*64, wn = (wv&1)*64;
  const int fr = lane & 15, fo = lane >> 4;
  f32x4 acc[4][4] = {};
  const int c0 = t*2, c1 = t*2+1;
  const int r0_ = c0>>2, k0_ = (c0&3)*8, r1_ = c1>>2, k1_ = (c1&3)*8;
  const u16* Ag0 = Ab + (long)(m0+r0_)*K + k0_;
  const u16* Ag1 = Ab + (long)(m0+r1_)*K + k1_;
  const u16* Bg0 = Bb + (long)(n0+r0_)*K + k0_;
  const u16* Bg1 = Bb + (long)(n0+r1_)*K + k1_;
  for (int k0 = 0; k0 < K; k0 += 32){
    __syncthreads();
    *(int4*)&As[r0_][k0_] = *(const int4*)(Ag0 + k0);
    *(int4*)&As[r1_][k1_] = *(const int4*)(Ag1 + k0);
    *(int4*)&Bs[r0_][k0_] = *(const int4*)(Bg0 + k0);
    *(int4*)&Bs[r1_][k1_] = *(const int4*)(Bg1 + k0);
    __syncthreads();
    bf16x8 af[4], bfv[4];
    #pragma unroll
    for (int i = 0; i < 4; ++i){
      af[i]  = *(const bf16x8*)&As[wm + i*16 + fr][fo*8];
      bfv[i] = *(const bf16x8*)&Bs[wn + i*16 + fr][fo*8];
    }
    #pragma unroll
    for (int mi = 0; mi < 4; ++mi)
      #pragma unroll
      for (int ni = 0; ni < 4; ++ni)
        acc[mi][ni] = __builtin_amdgcn_mfma_f32_16x16x32_bf16(af[mi], bfv[ni], acc[mi][ni], 0, 0, 0);
  }
  if (EPI == 0){
    float* Cf = (float*)Cv + (long)bI*sC;
    #pragma unroll
    for (int mi = 0; mi < 4; ++mi)
      #pragma unroll
      for (int ni = 0; ni < 4; ++ni){
        const int col = n0 + wn + ni*16 + fr;
        #pragma unroll
        for (int r = 0; r < 4; ++r){
          const int row = m0 + wm + mi*16 + fo*4 + r;
          Cf[(long)row*N + col] = acc[mi][ni][r];
        }
      }
  } else {
    // fold to NHWC: row=l=hb*32+wb, col=ck=c*64+kh*8+kw -> O[b][(hb*8+kh)*256+wb*8+kw][c]
    u16* O = (u16*)Cv;
    #pragma unroll
    for (int mi = 0; mi < 4; ++mi)
      #pragma unroll
      for (int ni = 0; ni < 4; ++ni){
        const int col = n0 + wn + ni*16 + fr;
        const int c = col >> 6, khh = (col>>3)&7, kww = col&7;
        #pragma unroll
        for (int r = 0; r < 4; ++r){
          const int row = m0 + wm + mi*16 + fo*4 + r;
          const int hb = row >> 5, wbb = row & 31;
          O[(((long)bI*65536 + (hb*8+khh)*256 + wbb*8 + kww)<<6) + c] = f2bf(acc[mi][ni][r]);
        }
      }
  }
}

// ---------------------------------------------------------------------------
// ff1: C[262144][256] = X[262144][64] * W1b^T, bias+GELU, bf16 out. No LDS.
// ---------------------------------------------------------------------------
__global__ __launch_bounds__(256,3) void ff1_mfma(
    const u16* __restrict__ X, const u16* __restrict__ W1b,
    const float* __restrict__ B1, u16* __restrict__ H1)
{
  const int t = threadIdx.x, lane = t & 63, wv = t >> 6;
  const long m0 = (long)blockIdx.x*128 + (wv>>1)*64;
  const int n0 = blockIdx.y*128 + (wv&1)*64;
  const int fr = lane & 15, fo = lane >> 4;
  f32x4 acc[4][4] = {};
  #pragma unroll
  for (int k0 = 0; k0 < 64; k0 += 32){
    bf16x8 af[4], bfv[4];
    #pragma unroll
    for (int i = 0; i < 4; ++i){
      af[i]  = *(const bf16x8*)(X   + (m0 + i*16 + fr)*64 + k0 + fo*8);
      bfv[i] = *(const bf16x8*)(W1b + (long)(n0 + i*16 + fr)*64 + k0 + fo*8);
    }
    #pragma unroll
    for (int mi = 0; mi < 4; ++mi)
      #pragma unroll
      for (int ni = 0; ni < 4; ++ni)
        acc[mi][ni] = __builtin_amdgcn_mfma_f32_16x16x32_bf16(af[mi], bfv[ni], acc[mi][ni], 0, 0, 0);
  }
  #pragma unroll
  for (int ni = 0; ni < 4; ++ni){
    const int col = n0 + ni*16 + fr;
    const float bc = B1[col];
    #pragma unroll
    for (int mi = 0; mi < 4; ++mi){
      const long row = m0 + mi*16 + fo*4;
      #pragma unroll
      for (int r = 0; r < 4; ++r)
        H1[(row + r)*256 + col] = f2bf(gelu_f(acc[mi][ni][r] + bc));
    }
  }
}

// ---------------------------------------------------------------------------
// ff2: C[262144][64] = H1[262144][256] * W2b^T, bias+GELU+residual, fp32 NCHW.
// ---------------------------------------------------------------------------
__global__ __launch_bounds__(256,3) void ff2_mfma(
    const u16* __restrict__ H1, const u16* __restrict__ W2b,
    const float* __restrict__ B2, const float* __restrict__ F,
    float* __restrict__ OUT)
{
  const int t = threadIdx.x, lane = t & 63, wv = t >> 6;
  const long m0 = (long)blockIdx.x*256 + wv*64;
  const int fr = lane & 15, fo = lane >> 4;
  f32x4 acc[4][4] = {};
  for (int k0 = 0; k0 < 256; k0 += 32){
    bf16x8 af[4], bfv[4];
    #pragma unroll
    for (int i = 0; i < 4; ++i){
      af[i]  = *(const bf16x8*)(H1  + (m0 + i*16 + fr)*256 + k0 + fo*8);
      bfv[i] = *(const bf16x8*)(W2b + (long)(i*16 + fr)*256 + k0 + fo*8);
    }
    #pragma unroll
    for (int mi = 0; mi < 4; ++mi)
      #pragma unroll
      for (int ni = 0; ni < 4; ++ni)
        acc[mi][ni] = __builtin_amdgcn_mfma_f32_16x16x32_bf16(af[mi], bfv[ni], acc[mi][ni], 0, 0, 0);
  }
  #pragma unroll
  for (int ni = 0; ni < 4; ++ni){
    const int c = ni*16 + fr;
    const float bc = B2[c];
    #pragma unroll
    for (int mi = 0; mi < 4; ++mi){
      const long p = m0 + mi*16 + fo*4;
      const int b = (int)(p >> 16), pp = (int)(p & 65535);
      const long idx = ((long)(b*64 + c))*65536 + pp;
      const f4 fres = *(const f4*)&F[idx];
      f4 o;
      #pragma unroll
      for (int r = 0; r < 4; ++r) o[r] = gelu_f(acc[mi][ni][r] + bc) + fres[r];
      *(f4*)&OUT[idx] = o;
    }
  }
}

// ---------------------------------------------------------------------------
__global__ __launch_bounds__(256) void cvt_w(
    const float* __restrict__ Wq, const float* __restrict__ Wk,
    u16* __restrict__ Oq, u16* __restrict__ Ok)
{
  const long i = ((long)blockIdx.x*256 + threadIdx.x)*4;
  const float* s = blockIdx.y ? Wk : Wq;
  u16* d = blockIdx.y ? Ok : Oq;
  f4 v = *(const f4*)&s[i];
  u16x4 o; o[0]=f2bf(v[0]); o[1]=f2bf(v[1]); o[2]=f2bf(v[2]); o[3]=f2bf(v[3]);
  *(u16x4*)&d[i] = o;
}

__global__ __launch_bounds__(256) void cvt_ffw(
    const float* __restrict__ W1, const float* __restrict__ W2,
    u16* __restrict__ O1, u16* __restrict__ O2)
{
  const long i = ((long)blockIdx.x*256 + threadIdx.x)*4;   // 16384 elems each
  const float* s = blockIdx.y ? W2 : W1;
  u16* d = blockIdx.y ? O2 : O1;
  f4 v = *(const f4*)&s[i];
  u16x4 o; o[0]=f2bf(v[0]); o[1]=f2bf(v[1]); o[2]=f2bf(v[2]); o[3]=f2bf(v[3]);
  *(u16x4*)&d[i] = o;
}

__global__ __launch_bounds__(256) void bn_stats(
    const float* __restrict__ X, float* __restrict__ sum, float* __restrict__ sumsq)
{
  const int t = threadIdx.x;
  const long r0 = (long)blockIdx.x*16;
  f4 s = {0,0,0,0}, q = {0,0,0,0};
  for (int r = 0; r < 16; ++r){
    f4 v = *(const f4*)&X[(r0 + r)*1024 + t*4];
    s += v; q += v*v;
  }
  atomicAdd(&sum[t*4+0], s[0]); atomicAdd(&sum[t*4+1], s[1]);
  atomicAdd(&sum[t*4+2], s[2]); atomicAdd(&sum[t*4+3], s[3]);
  atomicAdd(&sumsq[t*4+0], q[0]); atomicAdd(&sumsq[t*4+1], q[1]);
  atomicAdd(&sumsq[t*4+2], q[2]); atomicAdd(&sumsq[t*4+3], q[3]);
}

__global__ void bn_fin(const float* __restrict__ sum, const float* __restrict__ sumsq,
                       const float* __restrict__ g, const float* __restrict__ beta,
                       float* __restrict__ scale, float* __restrict__ shift)
{
  const int d = blockIdx.x*256 + threadIdx.x;
  if (d >= 1024) return;
  const float m  = sum[d]   * (1.f/4096.f);
  const float vv = sumsq[d] * (1.f/4096.f) - m*m;
  const float sc = g[d] * rsqrtf(vv + 1e-5f);
  scale[d] = sc;
  shift[d] = beta[d] - m*sc;
}

__global__ __launch_bounds__(256) void bn_apply(
    const float* __restrict__ X, const float* __restrict__ scale,
    const float* __restrict__ shift, u16* __restrict__ Y)
{
  const long i = ((long)blockIdx.x*256 + threadIdx.x)*4;
  f4 v = *(const f4*)&X[i];
  const int d = (int)(i & 1023);
  const f4 sc = *(const f4*)&scale[d];
  const f4 sh = *(const f4*)&shift[d];
  v = v*sc + sh;
  u16x4 o; o[0]=f2bf(v[0]); o[1]=f2bf(v[1]); o[2]=f2bf(v[2]); o[3]=f2bf(v[3]);
  *(u16x4*)&Y[i] = o;
}

__global__ __launch_bounds__(256) void softmax_k(
    const float* __restrict__ S, u16* __restrict__ P)
{
  const long row = blockIdx.x;
  const float* p = S + row*1024;
  const int t = threadIdx.x;
  f4 v = *(const f4*)&p[t*4];
  v *= 0.03125f;
  float mx = fmaxf(fmaxf(v[0],v[1]), fmaxf(v[2],v[3]));
  #pragma unroll
  for (int o = 1; o < 64; o <<= 1) mx = fmaxf(mx, __shfl_xor(mx, o));
  __shared__ float red[4], red2[4];
  if ((t & 63) == 0) red[t>>6] = mx;
  __syncthreads();
  mx = fmaxf(fmaxf(red[0],red[1]), fmaxf(red[2],red[3]));
  f4 e;
  e[0]=__expf(v[0]-mx); e[1]=__expf(v[1]-mx); e[2]=__expf(v[2]-mx); e[3]=__expf(v[3]-mx);
  float sm = e[0]+e[1]+e[2]+e[3];
  #pragma unroll
  for (int o = 1; o < 64; o <<= 1) sm += __shfl_xor(sm, o);
  if ((t & 63) == 0) red2[t>>6] = sm;
  __syncthreads();
  sm = red2[0]+red2[1]+red2[2]+red2[3];
  const float inv = 1.0f/sm;
  u16x4 o4; o4[0]=f2bf(e[0]*inv); o4[1]=f2bf(e[1]*inv); o4[2]=f2bf(e[2]*inv); o4[3]=f2bf(e[3]*inv);
  *(u16x4*)&P[row*1024 + t*4] = o4;
}

// ---------------------------------------------------------------------------
extern "C" void kernel_launch(void* const* d_in, const int* in_sizes, int n_in,
                              void* d_out, int out_size, void* d_ws, size_t ws_size,
                              hipStream_t stream)
{
  const float* feat  = (const float*)d_in[0];
  const float* w_enc = (const float*)d_in[1];
  const float* b_enc = (const float*)d_in[2];
  const float* w_k   = (const float*)d_in[3];
  const float* b_k   = (const float*)d_in[4];
  const float* w_v   = (const float*)d_in[5];
  const float* b_v   = (const float*)d_in[6];
  const float* fcq_w = (const float*)d_in[7];
  // d_in[8] fcq_b, d_in[10] fck_b: cancelled exactly by train-mode BN.
  const float* fck_w = (const float*)d_in[9];
  const float* bnq_g = (const float*)d_in[11];
  const float* bnq_b = (const float*)d_in[12];
  const float* bnk_g = (const float*)d_in[13];
  const float* bnk_b = (const float*)d_in[14];
  const float* ff1w  = (const float*)d_in[15];
  const float* ff1b  = (const float*)d_in[16];
  const float* ff2w  = (const float*)d_in[17];
  const float* ff2b  = (const float*)d_in[18];

  char* ws = (char*)d_ws;
  u16*   Aq      = (u16*)  (ws);                   // [0,32)  MB [B][L][4096]
  u16*   Ak      = (u16*)  (ws + (32ull<<20));     // [32,64)
  u16*   Vc      = (u16*)  (ws + (64ull<<20));     // [64,96)  [B][4096][L]
  u16*   Wq      = (u16*)  (ws + (96ull<<20));     // [96,104)
  u16*   Wk      = (u16*)  (ws + (104ull<<20));    // [104,112)
  u16*   q_bf    = (u16*)  (ws + (112ull<<20));    // [112,120)
  u16*   k_bf    = (u16*)  (ws + (120ull<<20));    // [120,128)
  float* q_raw   = (float*)(ws + (128ull<<20));    // [128,144)
  float* k_raw   = (float*)(ws + (144ull<<20));    // [144,160)
  float* scores  = (float*)(ws + (160ull<<20));    // [160,176)
  u16*   attn    = (u16*)  (ws + (176ull<<20));    // [176,184)
  u16*   out_nhwc= (u16*)  (ws + (184ull<<20));    // [184,216) [B][65536][64]
  u16*   NX      = (u16*)  (ws + (128ull<<20));    // [128,160) transient
  u16*   Vl      = (u16*)  (ws + (160ull<<20));    // [160,192) transient
  u16*   Wt      = (u16*)  (ws + (216ull<<20));    // +221KB
  float* stats   = (float*)(ws + (217ull<<20));    // 32KB
  u16*   W1b     = (u16*)  (ws + (218ull<<20));    // 32KB [256][64] bf16
  u16*   W2b     = (u16*)  (ws + (218ull<<20) + 65536); // 32KB [64][256] bf16
  u16*   h1      = (u16*)  (ws);                   // [0,128) reuse (Aq..k_bf dead by ff1)
  float* sum_q = stats,        *sumsq_q = stats+1024;
  float* sum_k = stats+2048,   *sumsq_k = stats+3072;
  float* scale_q = stats+4096, *shift_q = stats+5120;
  float* scale_k = stats+6144, *shift_k = stats+7168;

  hipMemsetAsync(stats, 0, 4096*sizeof(float), stream);

  to_nhwc<<<dim3(1024,4), 256, 0, stream>>>(feat, NX);
  wt_prep<<<dim3(432), 256, 0, stream>>>(w_enc, w_k, w_v, Wt);
  conv_mfma<<<dim3(16,32,4), 256, 0, stream>>>(NX, Wt, b_enc, b_k, b_v, Aq, Ak, Vl);
  v_tr<<<dim3(64,16,4), 256, 0, stream>>>(Vl, Vc);
  cvt_w<<<dim3(4096,2), 256, 0, stream>>>(fcq_w, fck_w, Wq, Wk);
  cvt_ffw<<<dim3(16,2), 256, 0, stream>>>(ff1w, ff2w, W1b, W2b);

  gemm_bt<0><<<dim3(8,8,4),  256, 0, stream>>>(Aq, 4194304, Wq, 0, q_raw, 1048576, 1024, 1024, 4096);
  gemm_bt<0><<<dim3(8,8,4),  256, 0, stream>>>(Ak, 4194304, Wk, 0, k_raw, 1048576, 1024, 1024, 4096);

  bn_stats<<<dim3(256), 256, 0, stream>>>(q_raw, sum_q, sumsq_q);
  bn_stats<<<dim3(256), 256, 0, stream>>>(k_raw, sum_k, sumsq_k);
  bn_fin<<<dim3(4), 256, 0, stream>>>(sum_q, sumsq_q, bnq_g, bnq_b, scale_q, shift_q);
  bn_fin<<<dim3(4), 256, 0, stream>>>(sum_k, sumsq_k, bnk_g, bnk_b, scale_k, shift_k);
  bn_apply<<<dim3(4096), 256, 0, stream>>>(q_raw, scale_q, shift_q, q_bf);
  bn_apply<<<dim3(4096), 256, 0, stream>>>(k_raw, scale_k, shift_k, k_bf);

  gemm_bt<0><<<dim3(8,8,4),  256, 0, stream>>>(q_bf, 1048576, k_bf, 1048576, scores, 1048576, 1024, 1024, 1024);
  softmax_k<<<dim3(4096), 256, 0, stream>>>(scores, attn);

  gemm_bt<1><<<dim3(8,32,4), 256, 0, stream>>>(attn, 1048576, Vc, 4194304, out_nhwc, 0, 1024, 4096, 1024);

  ff1_mfma<<<dim3(2048,2), 256, 0, stream>>>(out_nhwc, W1b, ff1b, h1);
  ff2_mfma<<<dim3(1024), 256, 0, stream>>>(h1, W2b, ff2b, feat, (float*)d_out);
}

// Round 5
// 695.251 us; speedup vs baseline: 2.5243x; 1.2211x over previous
//
#include <hip/hip_runtime.h>

typedef unsigned short u16;
typedef float f4 __attribute__((ext_vector_type(4)));
typedef float f32x4 __attribute__((ext_vector_type(4)));
typedef short bf16x8 __attribute__((ext_vector_type(8)));
typedef u16 u16x8 __attribute__((ext_vector_type(8)));
typedef u16 u16x4 __attribute__((ext_vector_type(4)));

__device__ __forceinline__ u16 f2bf(float f){
  unsigned u = __float_as_uint(f);
  u = (u + 0x7FFFu + ((u>>16)&1u)) >> 16;
  return (u16)u;
}
__device__ __forceinline__ float bf2f(u16 u){
  return __uint_as_float(((unsigned)u)<<16);
}
__device__ __forceinline__ float gelu_f(float x){
  return 0.5f*x*(1.0f+erff(x*0.70710678118654752440f));
}

// async global->LDS 16B (HK cast pattern; LDS dest is wave-uniform base + lane*16)
typedef __attribute__((address_space(1))) const unsigned int as1_cuint;
typedef __attribute__((address_space(3))) unsigned int as3_uint;
__device__ __forceinline__ void gload_lds16(const void* g, void* l){
  __builtin_amdgcn_global_load_lds((as1_cuint*)g, (as3_uint*)l, 16, 0, 0);
}

// ---------------------------------------------------------------------------
// feat NCHW fp32 -> NHWC bf16  ([4][256][256][64])
// ---------------------------------------------------------------------------
__global__ __launch_bounds__(256) void to_nhwc(
    const float* __restrict__ F, u16* __restrict__ O)
{
  __shared__ float tile[64][65];
  const int t = threadIdx.x, b = blockIdx.y;
  const long px0 = (long)blockIdx.x*64;
  const float* Fb = F + (long)b*64*65536;
  #pragma unroll
  for (int i = 0; i < 4; ++i){
    const int ch = (t>>4) + i*16;
    const int pxo = (t&15)*4;
    f4 v = *(const f4*)&Fb[(long)ch*65536 + px0 + pxo];
    tile[ch][pxo]=v[0]; tile[ch][pxo+1]=v[1]; tile[ch][pxo+2]=v[2]; tile[ch][pxo+3]=v[3];
  }
  __syncthreads();
  const int px = t & 63, ch0 = (t>>6)*16;
  u16x8 o0, o1;
  #pragma unroll
  for (int j = 0; j < 8; ++j){ o0[j]=f2bf(tile[ch0+j][px]); o1[j]=f2bf(tile[ch0+8+j][px]); }
  u16* Ob = O + ((long)b*65536 + px0 + px)*64 + ch0;
  *(u16x8*)Ob = o0; *(u16x8*)(Ob+8) = o1;
}

// ---------------------------------------------------------------------------
// conv weights -> Wt2[((dy*3+dx)*2+kc)*192 + n][32]  (fragment-contiguous bf16)
// n = g*64+co (g: 0=enc,1=k,2=v); elem = ci - kc*32.
// ---------------------------------------------------------------------------
__global__ __launch_bounds__(256) void wt_prep(
    const float* __restrict__ we, const float* __restrict__ wk,
    const float* __restrict__ wv, u16* __restrict__ Wt2)
{
  const int i = blockIdx.x*256 + threadIdx.x;   // 110592 total
  const int cio = i & 31;
  const int t1 = i >> 5;
  const int n  = t1 % 192;
  const int t2 = t1 / 192;
  const int kc = t2 & 1, p = t2 >> 1;
  const int dy = p/3, dx = p - dy*3;
  const int ci = kc*32 + cio;
  const float* W = (n < 64) ? we : (n < 128) ? wk : wv;
  const int co = n & 63;
  Wt2[i] = f2bf(W[((co*64 + ci)*3 + dy)*3 + dx]);
}

// ---------------------------------------------------------------------------
// MFMA implicit-GEMM conv, barrier-free main loop: halo staged once (1 barrier),
// weight fragments loaded per-wave straight from L2 (coalesced 1KB/fragment).
// ---------------------------------------------------------------------------
__global__ __launch_bounds__(256,2) void conv_mfma(
    const u16* __restrict__ X, const u16* __restrict__ Wt2,
    const float* __restrict__ be, const float* __restrict__ bk, const float* __restrict__ bv,
    u16* __restrict__ Aq, u16* __restrict__ Ak, u16* __restrict__ Vl)
{
  __shared__ __align__(16) u16 halo[10*18*64];   // 23040 B (only LDS use)
  const int t = threadIdx.x, lane = t & 63, wvi = t >> 6;
  const int bx = blockIdx.x, by = blockIdx.y, b = blockIdx.z;
  const int x0 = bx*16, y0 = by*8;
  const u16* Xb = X + (long)b*4194304;

  #pragma unroll
  for (int j = 0; j < 6; ++j){
    const int id = t + j*256;
    if (id < 1440){
      const int row = id / 144, rem = id - row*144, col = rem >> 3, ck = rem & 7;
      const int y = y0 - 1 + row, x = x0 - 1 + col;
      int4 v = {0,0,0,0};
      if ((unsigned)y < 256u && (unsigned)x < 256u)
        v = *(const int4*)(Xb + ((long)y*256 + x)*64 + ck*8);
      *(int4*)&halo[((row*18 + col)*8 + (ck ^ (col&7)))*8] = v;
    }
  }
  __syncthreads();   // the only barrier

  const int wm4 = (wvi>>1)*4;          // pixel-row base
  const int wn  = (wvi&1)*96;          // cout base
  const int fr = lane & 15, fo = lane >> 4;
  f32x4 acc[4][6] = {};

  #pragma unroll
  for (int dy = 0; dy < 3; ++dy)
  #pragma unroll
  for (int dx = 0; dx < 3; ++dx){
    const int p = dy*3 + dx;
    #pragma unroll
    for (int kc = 0; kc < 2; ++kc){
      bf16x8 af[4], bfv[6];
      const u16* wp = Wt2 + ((long)(p*2 + kc)*192 + wn + fr)*32 + fo*8;
      #pragma unroll
      for (int ni = 0; ni < 6; ++ni)
        bfv[ni] = *(const bf16x8*)(wp + ni*16*32);
      #pragma unroll
      for (int mi = 0; mi < 4; ++mi){
        const int row = wm4 + mi + dy;
        const int col = fr + dx;
        af[mi] = *(const bf16x8*)&halo[((row*18 + col)*8 + ((kc*4+fo) ^ (col&7)))*8];
      }
      #pragma unroll
      for (int mi = 0; mi < 4; ++mi)
        #pragma unroll
        for (int ni = 0; ni < 6; ++ni)
          acc[mi][ni] = __builtin_amdgcn_mfma_f32_16x16x32_bf16(af[mi], bfv[ni], acc[mi][ni], 0, 0, 0);
    }
  }

  // epilogue: bias + GELU + bf16, unfolded layouts (verified round 2)
  const int c0 = fo*4;
  const int l  = by*32 + bx*2 + (c0>>3);
  const int kw0 = c0 & 7;
  #pragma unroll
  for (int ni = 0; ni < 6; ++ni){
    const int n = wn + ni*16 + fr;
    const int g = n >> 6, co = n & 63;
    const float bias = (g==0) ? be[co] : (g==1) ? bk[co] : bv[co];
    #pragma unroll
    for (int mi = 0; mi < 4; ++mi){
      const int r = wm4 + mi;
      u16x4 o;
      #pragma unroll
      for (int rg = 0; rg < 4; ++rg) o[rg] = f2bf(gelu_f(acc[mi][ni][rg] + bias));
      const long base = ((long)b*1024 + l)*4096 + co*64 + r*8 + kw0;
      if (g == 0)      *(u16x4*)(Aq + base) = o;
      else if (g == 1) *(u16x4*)(Ak + base) = o;
      else             *(u16x4*)(Vl + base) = o;
    }
  }
}

// ---------------------------------------------------------------------------
// V transpose: [b][l=1024][ck=4096] -> [b][ck][l]
// ---------------------------------------------------------------------------
__global__ __launch_bounds__(256) void v_tr(
    const u16* __restrict__ S, u16* __restrict__ D)
{
  __shared__ u16 tl[64][72];
  const int t = threadIdx.x, b = blockIdx.z;
  const int ck0 = blockIdx.x*64, l0 = blockIdx.y*64;
  const u16* Sb = S + (long)b*4194304;
  u16* Db = D + (long)b*4194304;
  #pragma unroll
  for (int j = 0; j < 2; ++j){
    const int li = (t>>3) + j*32, cko = (t&7)*8;
    *(u16x8*)&tl[li][cko] = *(const u16x8*)(Sb + (long)(l0+li)*4096 + ck0 + cko);
  }
  __syncthreads();
  #pragma unroll
  for (int j = 0; j < 2; ++j){
    const int cki = (t>>3) + j*32, lo = (t&7)*8;
    u16x8 v;
    #pragma unroll
    for (int e = 0; e < 8; ++e) v[e] = tl[lo+e][cki];
    *(u16x8*)(Db + (long)(ck0+cki)*1024 + l0 + lo) = v;
  }
}

// ---------------------------------------------------------------------------
// bf16 MFMA GEMM (m97 structure): C[b]=A[b](MxK)*B[b]^T, 128x128 tile, BK=32,
// linear [128][32] LDS staged via global_load_lds width=16.
// zshB: B batch index = bI >> zshB (lets q/k proj share one launch).
// EPI 0: fp32 C. EPI 1: NHWC fold bf16.
// ---------------------------------------------------------------------------
template<int EPI>
__global__ __launch_bounds__(256,2) void gemm_bt(
    const u16* __restrict__ A, long sA,
    const u16* __restrict__ B, long sB, const int zshB,
    void* __restrict__ Cv, long sC,
    const int M, const int N, const int K)
{
  const int bI = blockIdx.z;
  const u16* Ab = A + (long)bI*sA;
  const u16* Bb = B + (long)(bI>>zshB)*sB;
  const int m0 = blockIdx.x*128, n0 = blockIdx.y*128;
  __shared__ __align__(16) u16 As[128*32];
  __shared__ __align__(16) u16 Bs[128*32];
  const int t = threadIdx.x, lane = t & 63, wv = t >> 6;
  const int wm = (wv>>1)*64, wn = (wv&1)*64;
  const int fr = lane & 15, fo = lane >> 4;
  f32x4 acc[4][4] = {};
  // staging chunks: chunk c -> row c>>2, col (c&3)*8; LDS byte off = c*16
  const int c0 = wv*128 + lane, c1 = c0 + 64;
  const u16* Ag0 = Ab + (long)(m0 + (c0>>2))*K + (c0&3)*8;
  const u16* Ag1 = Ab + (long)(m0 + (c1>>2))*K + (c1&3)*8;
  const u16* Bg0 = Bb + (long)(n0 + (c0>>2))*K + (c0&3)*8;
  const u16* Bg1 = Bb + (long)(n0 + (c1>>2))*K + (c1&3)*8;
  u16* lA0 = &As[wv*1024];        // wave-uniform LDS bases
  u16* lA1 = &As[wv*1024 + 512];
  u16* lB0 = &Bs[wv*1024];
  u16* lB1 = &Bs[wv*1024 + 512];
  for (int k0 = 0; k0 < K; k0 += 32){
    __syncthreads();
    gload_lds16(Ag0 + k0, lA0);
    gload_lds16(Ag1 + k0, lA1);
    gload_lds16(Bg0 + k0, lB0);
    gload_lds16(Bg1 + k0, lB1);
    __syncthreads();
    bf16x8 af[4], bfv[4];
    #pragma unroll
    for (int i = 0; i < 4; ++i){
      af[i]  = *(const bf16x8*)&As[(wm + i*16 + fr)*32 + fo*8];
      bfv[i] = *(const bf16x8*)&Bs[(wn + i*16 + fr)*32 + fo*8];
    }
    #pragma unroll
    for (int mi = 0; mi < 4; ++mi)
      #pragma unroll
      for (int ni = 0; ni < 4; ++ni)
        acc[mi][ni] = __builtin_amdgcn_mfma_f32_16x16x32_bf16(af[mi], bfv[ni], acc[mi][ni], 0, 0, 0);
  }
  if (EPI == 0){
    float* Cf = (float*)Cv + (long)bI*sC;
    #pragma unroll
    for (int mi = 0; mi < 4; ++mi)
      #pragma unroll
      for (int ni = 0; ni < 4; ++ni){
        const int col = n0 + wn + ni*16 + fr;
        #pragma unroll
        for (int r = 0; r < 4; ++r){
          const int row = m0 + wm + mi*16 + fo*4 + r;
          Cf[(long)row*N + col] = acc[mi][ni][r];
        }
      }
  } else {
    // fold to NHWC: row=l=hb*32+wb, col=ck=c*64+kh*8+kw -> O[b][(hb*8+kh)*256+wb*8+kw][c]
    u16* O = (u16*)Cv;
    #pragma unroll
    for (int mi = 0; mi < 4; ++mi)
      #pragma unroll
      for (int ni = 0; ni < 4; ++ni){
        const int col = n0 + wn + ni*16 + fr;
        const int c = col >> 6, khh = (col>>3)&7, kww = col&7;
        #pragma unroll
        for (int r = 0; r < 4; ++r){
          const int row = m0 + wm + mi*16 + fo*4 + r;
          const int hb = row >> 5, wbb = row & 31;
          O[(((long)bI*65536 + (hb*8+khh)*256 + wbb*8 + kww)<<6) + c] = f2bf(acc[mi][ni][r]);
        }
      }
  }
}

// ---------------------------------------------------------------------------
// ff1: C[262144][256] = X[262144][64] * W1b^T, bias+GELU, bf16 out. No LDS.
// ---------------------------------------------------------------------------
__global__ __launch_bounds__(256,3) void ff1_mfma(
    const u16* __restrict__ X, const u16* __restrict__ W1b,
    const float* __restrict__ B1, u16* __restrict__ H1)
{
  const int t = threadIdx.x, lane = t & 63, wv = t >> 6;
  const long m0 = (long)blockIdx.x*128 + (wv>>1)*64;
  const int n0 = blockIdx.y*128 + (wv&1)*64;
  const int fr = lane & 15, fo = lane >> 4;
  f32x4 acc[4][4] = {};
  #pragma unroll
  for (int k0 = 0; k0 < 64; k0 += 32){
    bf16x8 af[4], bfv[4];
    #pragma unroll
    for (int i = 0; i < 4; ++i){
      af[i]  = *(const bf16x8*)(X   + (m0 + i*16 + fr)*64 + k0 + fo*8);
      bfv[i] = *(const bf16x8*)(W1b + (long)(n0 + i*16 + fr)*64 + k0 + fo*8);
    }
    #pragma unroll
    for (int mi = 0; mi < 4; ++mi)
      #pragma unroll
      for (int ni = 0; ni < 4; ++ni)
        acc[mi][ni] = __builtin_amdgcn_mfma_f32_16x16x32_bf16(af[mi], bfv[ni], acc[mi][ni], 0, 0, 0);
  }
  #pragma unroll
  for (int ni = 0; ni < 4; ++ni){
    const int col = n0 + ni*16 + fr;
    const float bc = B1[col];
    #pragma unroll
    for (int mi = 0; mi < 4; ++mi){
      const long row = m0 + mi*16 + fo*4;
      #pragma unroll
      for (int r = 0; r < 4; ++r)
        H1[(row + r)*256 + col] = f2bf(gelu_f(acc[mi][ni][r] + bc));
    }
  }
}

// ---------------------------------------------------------------------------
// ff2: C[262144][64] = H1[262144][256] * W2b^T, bias+GELU+residual, fp32 NCHW.
// ---------------------------------------------------------------------------
__global__ __launch_bounds__(256,3) void ff2_mfma(
    const u16* __restrict__ H1, const u16* __restrict__ W2b,
    const float* __restrict__ B2, const float* __restrict__ F,
    float* __restrict__ OUT)
{
  const int t = threadIdx.x, lane = t & 63, wv = t >> 6;
  const long m0 = (long)blockIdx.x*256 + wv*64;
  const int fr = lane & 15, fo = lane >> 4;
  f32x4 acc[4][4] = {};
  for (int k0 = 0; k0 < 256; k0 += 32){
    bf16x8 af[4], bfv[4];
    #pragma unroll
    for (int i = 0; i < 4; ++i){
      af[i]  = *(const bf16x8*)(H1  + (m0 + i*16 + fr)*256 + k0 + fo*8);
      bfv[i] = *(const bf16x8*)(W2b + (long)(i*16 + fr)*256 + k0 + fo*8);
    }
    #pragma unroll
    for (int mi = 0; mi < 4; ++mi)
      #pragma unroll
      for (int ni = 0; ni < 4; ++ni)
        acc[mi][ni] = __builtin_amdgcn_mfma_f32_16x16x32_bf16(af[mi], bfv[ni], acc[mi][ni], 0, 0, 0);
  }
  #pragma unroll
  for (int ni = 0; ni < 4; ++ni){
    const int c = ni*16 + fr;
    const float bc = B2[c];
    #pragma unroll
    for (int mi = 0; mi < 4; ++mi){
      const long p = m0 + mi*16 + fo*4;
      const int b = (int)(p >> 16), pp = (int)(p & 65535);
      const long idx = ((long)(b*64 + c))*65536 + pp;
      const f4 fres = *(const f4*)&F[idx];
      f4 o;
      #pragma unroll
      for (int r = 0; r < 4; ++r) o[r] = gelu_f(acc[mi][ni][r] + bc) + fres[r];
      *(f4*)&OUT[idx] = o;
    }
  }
}

// ---------------------------------------------------------------------------
__global__ __launch_bounds__(256) void cvt_w(
    const float* __restrict__ Wq, const float* __restrict__ Wk,
    u16* __restrict__ Oq, u16* __restrict__ Ok)
{
  const long i = ((long)blockIdx.x*256 + threadIdx.x)*4;
  const float* s = blockIdx.y ? Wk : Wq;
  u16* d = blockIdx.y ? Ok : Oq;
  f4 v = *(const f4*)&s[i];
  u16x4 o; o[0]=f2bf(v[0]); o[1]=f2bf(v[1]); o[2]=f2bf(v[2]); o[3]=f2bf(v[3]);
  *(u16x4*)&d[i] = o;
}

__global__ __launch_bounds__(256) void cvt_ffw(
    const float* __restrict__ W1, const float* __restrict__ W2,
    u16* __restrict__ O1, u16* __restrict__ O2)
{
  const long i = ((long)blockIdx.x*256 + threadIdx.x)*4;
  const float* s = blockIdx.y ? W2 : W1;
  u16* d = blockIdx.y ? O2 : O1;
  f4 v = *(const f4*)&s[i];
  u16x4 o; o[0]=f2bf(v[0]); o[1]=f2bf(v[1]); o[2]=f2bf(v[2]); o[3]=f2bf(v[3]);
  *(u16x4*)&d[i] = o;
}

// ---------------------------------------------------------------------------
// BN (q & k merged via blockIdx.y; q_raw/k_raw and stat slots are contiguous)
// ---------------------------------------------------------------------------
__global__ __launch_bounds__(256) void bn_stats2(
    const float* __restrict__ Xq, float* __restrict__ stats)
{
  const int sel = blockIdx.y;
  const float* X = Xq + (long)sel*4194304;
  float* sum   = stats + sel*2048;
  float* sumsq = sum + 1024;
  const int t = threadIdx.x;
  const long r0 = (long)blockIdx.x*16;
  f4 s = {0,0,0,0}, q = {0,0,0,0};
  for (int r = 0; r < 16; ++r){
    f4 v = *(const f4*)&X[(r0 + r)*1024 + t*4];
    s += v; q += v*v;
  }
  atomicAdd(&sum[t*4+0], s[0]); atomicAdd(&sum[t*4+1], s[1]);
  atomicAdd(&sum[t*4+2], s[2]); atomicAdd(&sum[t*4+3], s[3]);
  atomicAdd(&sumsq[t*4+0], q[0]); atomicAdd(&sumsq[t*4+1], q[1]);
  atomicAdd(&sumsq[t*4+2], q[2]); atomicAdd(&sumsq[t*4+3], q[3]);
}

__global__ void bn_fin2(float* __restrict__ stats,
                        const float* __restrict__ gq, const float* __restrict__ bq,
                        const float* __restrict__ gk, const float* __restrict__ bk)
{
  const int sel = blockIdx.y;
  const int d = blockIdx.x*256 + threadIdx.x;
  if (d >= 1024) return;
  const float* sum   = stats + sel*2048;
  const float* sumsq = sum + 1024;
  const float* g    = sel ? gk : gq;
  const float* beta = sel ? bk : bq;
  const float m  = sum[d]   * (1.f/4096.f);
  const float vv = sumsq[d] * (1.f/4096.f) - m*m;
  const float sc = g[d] * rsqrtf(vv + 1e-5f);
  stats[4096 + sel*2048 + d]        = sc;              // scale
  stats[4096 + sel*2048 + 1024 + d] = beta[d] - m*sc;  // shift
}

__global__ __launch_bounds__(256) void bn_apply2(
    const float* __restrict__ Xq, const float* __restrict__ stats,
    u16* __restrict__ Yq)
{
  const int sel = blockIdx.y;
  const float* X = Xq + (long)sel*4194304;
  u16* Y = Yq + (long)sel*4194304;
  const float* scale = stats + 4096 + sel*2048;
  const float* shift = scale + 1024;
  const long i = ((long)blockIdx.x*256 + threadIdx.x)*4;
  f4 v = *(const f4*)&X[i];
  const int d = (int)(i & 1023);
  const f4 sc = *(const f4*)&scale[d];
  const f4 sh = *(const f4*)&shift[d];
  v = v*sc + sh;
  u16x4 o; o[0]=f2bf(v[0]); o[1]=f2bf(v[1]); o[2]=f2bf(v[2]); o[3]=f2bf(v[3]);
  *(u16x4*)&Yq[(long)sel*4194304 + i] = o;
  (void)Y;
}

__global__ __launch_bounds__(256) void softmax_k(
    const float* __restrict__ S, u16* __restrict__ P)
{
  const long row = blockIdx.x;
  const float* p = S + row*1024;
  const int t = threadIdx.x;
  f4 v = *(const f4*)&p[t*4];
  v *= 0.03125f;
  float mx = fmaxf(fmaxf(v[0],v[1]), fmaxf(v[2],v[3]));
  #pragma unroll
  for (int o = 1; o < 64; o <<= 1) mx = fmaxf(mx, __shfl_xor(mx, o));
  __shared__ float red[4], red2[4];
  if ((t & 63) == 0) red[t>>6] = mx;
  __syncthreads();
  mx = fmaxf(fmaxf(red[0],red[1]), fmaxf(red[2],red[3]));
  f4 e;
  e[0]=__expf(v[0]-mx); e[1]=__expf(v[1]-mx); e[2]=__expf(v[2]-mx); e[3]=__expf(v[3]-mx);
  float sm = e[0]+e[1]+e[2]+e[3];
  #pragma unroll
  for (int o = 1; o < 64; o <<= 1) sm += __shfl_xor(sm, o);
  if ((t & 63) == 0) red2[t>>6] = sm;
  __syncthreads();
  sm = red2[0]+red2[1]+red2[2]+red2[3];
  const float inv = 1.0f/sm;
  u16x4 o4; o4[0]=f2bf(e[0]*inv); o4[1]=f2bf(e[1]*inv); o4[2]=f2bf(e[2]*inv); o4[3]=f2bf(e[3]*inv);
  *(u16x4*)&P[row*1024 + t*4] = o4;
}

// ---------------------------------------------------------------------------
extern "C" void kernel_launch(void* const* d_in, const int* in_sizes, int n_in,
                              void* d_out, int out_size, void* d_ws, size_t ws_size,
                              hipStream_t stream)
{
  const float* feat  = (const float*)d_in[0];
  const float* w_enc = (const float*)d_in[1];
  const float* b_enc = (const float*)d_in[2];
  const float* w_k   = (const float*)d_in[3];
  const float* b_k   = (const float*)d_in[4];
  const float* w_v   = (const float*)d_in[5];
  const float* b_v   = (const float*)d_in[6];
  const float* fcq_w = (const float*)d_in[7];
  // d_in[8] fcq_b, d_in[10] fck_b: cancelled exactly by train-mode BN.
  const float* fck_w = (const float*)d_in[9];
  const float* bnq_g = (const float*)d_in[11];
  const float* bnq_b = (const float*)d_in[12];
  const float* bnk_g = (const float*)d_in[13];
  const float* bnk_b = (const float*)d_in[14];
  const float* ff1w  = (const float*)d_in[15];
  const float* ff1b  = (const float*)d_in[16];
  const float* ff2w  = (const float*)d_in[17];
  const float* ff2b  = (const float*)d_in[18];

  char* ws = (char*)d_ws;
  u16*   Aq      = (u16*)  (ws);                   // [0,32)  MB [B][L][4096]   (Ak follows contiguously)
  u16*   Ak      = (u16*)  (ws + (32ull<<20));     // [32,64)
  u16*   Vc      = (u16*)  (ws + (64ull<<20));     // [64,96)  [B][4096][L]
  u16*   Wq      = (u16*)  (ws + (96ull<<20));     // [96,104)  (Wk follows)
  u16*   Wk      = (u16*)  (ws + (104ull<<20));    // [104,112)
  u16*   q_bf    = (u16*)  (ws + (112ull<<20));    // [112,120) (k_bf follows)
  u16*   k_bf    = (u16*)  (ws + (120ull<<20));    // [120,128)
  float* q_raw   = (float*)(ws + (128ull<<20));    // [128,144) (k_raw follows)
  float* k_raw   = (float*)(ws + (144ull<<20));    // [144,160)
  float* scores  = (float*)(ws + (160ull<<20));    // [160,176)
  u16*   attn    = (u16*)  (ws + (176ull<<20));    // [176,184)
  u16*   out_nhwc= (u16*)  (ws + (184ull<<20));    // [184,216) [B][65536][64]
  u16*   NX      = (u16*)  (ws + (128ull<<20));    // [128,160) transient (dead before q_raw)
  u16*   Vl      = (u16*)  (ws + (160ull<<20));    // [160,192) transient (dead before scores)
  u16*   Wt2     = (u16*)  (ws + (216ull<<20));    // +221KB
  float* stats   = (float*)(ws + (217ull<<20));    // 32KB
  u16*   W1b     = (u16*)  (ws + (218ull<<20));    // 32KB [256][64] bf16
  u16*   W2b     = (u16*)  (ws + (218ull<<20) + 65536); // 32KB [64][256] bf16
  u16*   h1      = (u16*)  (ws);                   // [0,128) reuse (Aq..k_bf dead by ff1)

  hipMemsetAsync(stats, 0, 4096*sizeof(float), stream);

  to_nhwc<<<dim3(1024,4), 256, 0, stream>>>(feat, NX);
  wt_prep<<<dim3(432), 256, 0, stream>>>(w_enc, w_k, w_v, Wt2);
  conv_mfma<<<dim3(16,32,4), 256, 0, stream>>>(NX, Wt2, b_enc, b_k, b_v, Aq, Ak, Vl);
  v_tr<<<dim3(64,16,4), 256, 0, stream>>>(Vl, Vc);
  cvt_w<<<dim3(4096,2), 256, 0, stream>>>(fcq_w, fck_w, Wq, Wk);
  cvt_ffw<<<dim3(16,2), 256, 0, stream>>>(ff1w, ff2w, W1b, W2b);

  // merged q+k projections: z=0..3 -> Aq*Wq^T -> q_raw; z=4..7 -> Ak*Wk^T -> k_raw
  gemm_bt<0><<<dim3(8,8,8),  256, 0, stream>>>(Aq, 4194304, Wq, 4194304, 2,
                                               q_raw, 1048576, 1024, 1024, 4096);

  bn_stats2<<<dim3(256,2), 256, 0, stream>>>(q_raw, stats);
  bn_fin2<<<dim3(4,2), 256, 0, stream>>>(stats, bnq_g, bnq_b, bnk_g, bnk_b);
  bn_apply2<<<dim3(4096,2), 256, 0, stream>>>(q_raw, stats, q_bf);

  gemm_bt<0><<<dim3(8,8,4),  256, 0, stream>>>(q_bf, 1048576, k_bf, 1048576, 0,
                                               scores, 1048576, 1024, 1024, 1024);
  softmax_k<<<dim3(4096), 256, 0, stream>>>(scores, attn);

  gemm_bt<1><<<dim3(8,32,4), 256, 0, stream>>>(attn, 1048576, Vc, 4194304, 0,
                                               out_nhwc, 0, 1024, 4096, 1024);

  ff1_mfma<<<dim3(2048,2), 256, 0, stream>>>(out_nhwc, W1b, ff1b, h1);
  ff2_mfma<<<dim3(1024), 256, 0, stream>>>(h1, W2b, ff2b, feat, (float*)d_out);
}

// Round 6
// 578.923 us; speedup vs baseline: 3.0316x; 1.2009x over previous
//
#include <hip/hip_runtime.h>

typedef unsigned short u16;
typedef float f4 __attribute__((ext_vector_type(4)));
typedef float f32x4 __attribute__((ext_vector_type(4)));
typedef short bf16x8 __attribute__((ext_vector_type(8)));
typedef u16 u16x8 __attribute__((ext_vector_type(8)));
typedef u16 u16x4 __attribute__((ext_vector_type(4)));

__device__ __forceinline__ u16 f2bf(float f){
  unsigned u = __float_as_uint(f);
  u = (u + 0x7FFFu + ((u>>16)&1u)) >> 16;
  return (u16)u;
}
__device__ __forceinline__ float bf2f(u16 u){
  return __uint_as_float(((unsigned)u)<<16);
}
// tanh-form GELU: max |dev| vs exact erf-GELU ~1e-3 (threshold is 0.108).
// ~10 cheap VALU ops (v_exp + v_rcp), no libm erff polynomial.
__device__ __forceinline__ float gelu_f(float x){
  float y = 1.5957691216057308f*(x + 0.044715f*x*x*x);  // 2*sqrt(2/pi)*(x+ax^3)
  y = fminf(y, 30.0f);                                   // avoid inf/inf
  float t = __expf(y);                                   // e^{2u}
  float r = __builtin_amdgcn_rcpf(t + 1.0f);
  return 0.5f*x*(1.0f + (t - 1.0f)*r);                   // 0.5x(1+tanh(u))
}

// async global->LDS 16B (LDS dest is wave-uniform base + lane*16)
typedef __attribute__((address_space(1))) const unsigned int as1_cuint;
typedef __attribute__((address_space(3))) unsigned int as3_uint;
__device__ __forceinline__ void gload_lds16(const void* g, void* l){
  __builtin_amdgcn_global_load_lds((as1_cuint*)g, (as3_uint*)l, 16, 0, 0);
}

// ---------------------------------------------------------------------------
// feat NCHW fp32 -> NHWC bf16  ([4][256][256][64])
// ---------------------------------------------------------------------------
__global__ __launch_bounds__(256) void to_nhwc(
    const float* __restrict__ F, u16* __restrict__ O)
{
  __shared__ float tile[64][65];
  const int t = threadIdx.x, b = blockIdx.y;
  const long px0 = (long)blockIdx.x*64;
  const float* Fb = F + (long)b*64*65536;
  #pragma unroll
  for (int i = 0; i < 4; ++i){
    const int ch = (t>>4) + i*16;
    const int pxo = (t&15)*4;
    f4 v = *(const f4*)&Fb[(long)ch*65536 + px0 + pxo];
    tile[ch][pxo]=v[0]; tile[ch][pxo+1]=v[1]; tile[ch][pxo+2]=v[2]; tile[ch][pxo+3]=v[3];
  }
  __syncthreads();
  const int px = t & 63, ch0 = (t>>6)*16;
  u16x8 o0, o1;
  #pragma unroll
  for (int j = 0; j < 8; ++j){ o0[j]=f2bf(tile[ch0+j][px]); o1[j]=f2bf(tile[ch0+8+j][px]); }
  u16* Ob = O + ((long)b*65536 + px0 + px)*64 + ch0;
  *(u16x8*)Ob = o0; *(u16x8*)(Ob+8) = o1;
}

// ---------------------------------------------------------------------------
// conv weights -> Wt2[((dy*3+dx)*2+kc)*192 + n][32]  (fragment-contiguous bf16)
// ---------------------------------------------------------------------------
__global__ __launch_bounds__(256) void wt_prep(
    const float* __restrict__ we, const float* __restrict__ wk,
    const float* __restrict__ wv, u16* __restrict__ Wt2)
{
  const int i = blockIdx.x*256 + threadIdx.x;   // 110592 total
  const int cio = i & 31;
  const int t1 = i >> 5;
  const int n  = t1 % 192;
  const int t2 = t1 / 192;
  const int kc = t2 & 1, p = t2 >> 1;
  const int dy = p/3, dx = p - dy*3;
  const int ci = kc*32 + cio;
  const float* W = (n < 64) ? we : (n < 128) ? wk : wv;
  const int co = n & 63;
  Wt2[i] = f2bf(W[((co*64 + ci)*3 + dy)*3 + dx]);
}

// ---------------------------------------------------------------------------
// MFMA implicit-GEMM conv. Occupancy build: each block does 8x16 px x 96 couts
// (cout half selected by blockIdx.y&1); wave acc = 4x3 (48 regs), VGPR capped
// by __launch_bounds__(256,4) -> 4 waves/SIMD (was 2).
// ---------------------------------------------------------------------------
__global__ __launch_bounds__(256,4) void conv_mfma(
    const u16* __restrict__ X, const u16* __restrict__ Wt2,
    const float* __restrict__ be, const float* __restrict__ bk, const float* __restrict__ bv,
    u16* __restrict__ Aq, u16* __restrict__ Ak, u16* __restrict__ Vl)
{
  __shared__ __align__(16) u16 halo[10*18*64];   // 23040 B
  const int t = threadIdx.x, lane = t & 63, wvi = t >> 6;
  const int bx = blockIdx.x, byf = blockIdx.y, b = blockIdx.z;
  const int ng = byf & 1, by = byf >> 1;
  const int x0 = bx*16, y0 = by*8;
  const u16* Xb = X + (long)b*4194304;

  #pragma unroll
  for (int j = 0; j < 6; ++j){
    const int id = t + j*256;
    if (id < 1440){
      const int row = id / 144, rem = id - row*144, col = rem >> 3, ck = rem & 7;
      const int y = y0 - 1 + row, x = x0 - 1 + col;
      int4 v = {0,0,0,0};
      if ((unsigned)y < 256u && (unsigned)x < 256u)
        v = *(const int4*)(Xb + ((long)y*256 + x)*64 + ck*8);
      *(int4*)&halo[((row*18 + col)*8 + (ck ^ (col&7)))*8] = v;
    }
  }
  __syncthreads();

  const int wm4 = (wvi>>1)*4;                 // pixel-row base
  const int wn  = ng*96 + (wvi&1)*48;         // cout base (48-wide per wave)
  const int fr = lane & 15, fo = lane >> 4;
  f32x4 acc[4][3] = {};

  #pragma unroll
  for (int dy = 0; dy < 3; ++dy)
  #pragma unroll
  for (int dx = 0; dx < 3; ++dx){
    const int p = dy*3 + dx;
    #pragma unroll
    for (int kc = 0; kc < 2; ++kc){
      bf16x8 af[4], bfv[3];
      const u16* wp = Wt2 + ((long)(p*2 + kc)*192 + wn + fr)*32 + fo*8;
      #pragma unroll
      for (int ni = 0; ni < 3; ++ni)
        bfv[ni] = *(const bf16x8*)(wp + ni*16*32);
      #pragma unroll
      for (int mi = 0; mi < 4; ++mi){
        const int row = wm4 + mi + dy;
        const int col = fr + dx;
        af[mi] = *(const bf16x8*)&halo[((row*18 + col)*8 + ((kc*4+fo) ^ (col&7)))*8];
      }
      #pragma unroll
      for (int mi = 0; mi < 4; ++mi)
        #pragma unroll
        for (int ni = 0; ni < 3; ++ni)
          acc[mi][ni] = __builtin_amdgcn_mfma_f32_16x16x32_bf16(af[mi], bfv[ni], acc[mi][ni], 0, 0, 0);
    }
  }

  // epilogue: bias + GELU + bf16, unfolded layouts
  const int c0 = fo*4;
  const int l  = by*32 + bx*2 + (c0>>3);
  const int kw0 = c0 & 7;
  #pragma unroll
  for (int ni = 0; ni < 3; ++ni){
    const int n = wn + ni*16 + fr;
    const int g = n >> 6, co = n & 63;
    const float bias = (g==0) ? be[co] : (g==1) ? bk[co] : bv[co];
    #pragma unroll
    for (int mi = 0; mi < 4; ++mi){
      const int r = wm4 + mi;
      u16x4 o;
      #pragma unroll
      for (int rg = 0; rg < 4; ++rg) o[rg] = f2bf(gelu_f(acc[mi][ni][rg] + bias));
      const long base = ((long)b*1024 + l)*4096 + co*64 + r*8 + kw0;
      if (g == 0)      *(u16x4*)(Aq + base) = o;
      else if (g == 1) *(u16x4*)(Ak + base) = o;
      else             *(u16x4*)(Vl + base) = o;
    }
  }
}

// ---------------------------------------------------------------------------
// V transpose: [b][l=1024][ck=4096] -> [b][ck][l]
// ---------------------------------------------------------------------------
__global__ __launch_bounds__(256) void v_tr(
    const u16* __restrict__ S, u16* __restrict__ D)
{
  __shared__ u16 tl[64][72];
  const int t = threadIdx.x, b = blockIdx.z;
  const int ck0 = blockIdx.x*64, l0 = blockIdx.y*64;
  const u16* Sb = S + (long)b*4194304;
  u16* Db = D + (long)b*4194304;
  #pragma unroll
  for (int j = 0; j < 2; ++j){
    const int li = (t>>3) + j*32, cko = (t&7)*8;
    *(u16x8*)&tl[li][cko] = *(const u16x8*)(Sb + (long)(l0+li)*4096 + ck0 + cko);
  }
  __syncthreads();
  #pragma unroll
  for (int j = 0; j < 2; ++j){
    const int cki = (t>>3) + j*32, lo = (t&7)*8;
    u16x8 v;
    #pragma unroll
    for (int e = 0; e < 8; ++e) v[e] = tl[lo+e][cki];
    *(u16x8*)(Db + (long)(ck0+cki)*1024 + l0 + lo) = v;
  }
}

// ---------------------------------------------------------------------------
// bf16 MFMA GEMM (m97 structure): C[b]=A[b](MxK)*B[b]^T, 128x128 tile, BK=32,
// linear [128][32] LDS staged via global_load_lds width=16.
// EPI 0: fp32 C. EPI 1: NHWC fold bf16. EPI 2: bf16 C + fused BN sum/sumsq.
// ---------------------------------------------------------------------------
template<int EPI>
__global__ __launch_bounds__(256,2) void gemm_bt(
    const u16* __restrict__ A, long sA,
    const u16* __restrict__ B, long sB, const int zshB,
    void* __restrict__ Cv, long sC,
    const int M, const int N, const int K,
    float* __restrict__ bnstats)
{
  const int bI = blockIdx.z;
  const u16* Ab = A + (long)bI*sA;
  const u16* Bb = B + (long)(bI>>zshB)*sB;
  const int m0 = blockIdx.x*128, n0 = blockIdx.y*128;
  __shared__ __align__(16) u16 As[128*32];
  __shared__ __align__(16) u16 Bs[128*32];
  const int t = threadIdx.x, lane = t & 63, wv = t >> 6;
  const int wm = (wv>>1)*64, wn = (wv&1)*64;
  const int fr = lane & 15, fo = lane >> 4;
  f32x4 acc[4][4] = {};
  const int c0 = wv*128 + lane, c1 = c0 + 64;
  const u16* Ag0 = Ab + (long)(m0 + (c0>>2))*K + (c0&3)*8;
  const u16* Ag1 = Ab + (long)(m0 + (c1>>2))*K + (c1&3)*8;
  const u16* Bg0 = Bb + (long)(n0 + (c0>>2))*K + (c0&3)*8;
  const u16* Bg1 = Bb + (long)(n0 + (c1>>2))*K + (c1&3)*8;
  u16* lA0 = &As[wv*1024];
  u16* lA1 = &As[wv*1024 + 512];
  u16* lB0 = &Bs[wv*1024];
  u16* lB1 = &Bs[wv*1024 + 512];
  for (int k0 = 0; k0 < K; k0 += 32){
    __syncthreads();
    gload_lds16(Ag0 + k0, lA0);
    gload_lds16(Ag1 + k0, lA1);
    gload_lds16(Bg0 + k0, lB0);
    gload_lds16(Bg1 + k0, lB1);
    __syncthreads();
    bf16x8 af[4], bfv[4];
    #pragma unroll
    for (int i = 0; i < 4; ++i){
      af[i]  = *(const bf16x8*)&As[(wm + i*16 + fr)*32 + fo*8];
      bfv[i] = *(const bf16x8*)&Bs[(wn + i*16 + fr)*32 + fo*8];
    }
    #pragma unroll
    for (int mi = 0; mi < 4; ++mi)
      #pragma unroll
      for (int ni = 0; ni < 4; ++ni)
        acc[mi][ni] = __builtin_amdgcn_mfma_f32_16x16x32_bf16(af[mi], bfv[ni], acc[mi][ni], 0, 0, 0);
  }
  if (EPI == 0){
    float* Cf = (float*)Cv + (long)bI*sC;
    #pragma unroll
    for (int mi = 0; mi < 4; ++mi)
      #pragma unroll
      for (int ni = 0; ni < 4; ++ni){
        const int col = n0 + wn + ni*16 + fr;
        #pragma unroll
        for (int r = 0; r < 4; ++r){
          const int row = m0 + wm + mi*16 + fo*4 + r;
          Cf[(long)row*N + col] = acc[mi][ni][r];
        }
      }
  } else if (EPI == 1) {
    // fold to NHWC: row=l=hb*32+wb, col=ck=c*64+kh*8+kw -> O[b][(hb*8+kh)*256+wb*8+kw][c]
    u16* O = (u16*)Cv;
    #pragma unroll
    for (int mi = 0; mi < 4; ++mi)
      #pragma unroll
      for (int ni = 0; ni < 4; ++ni){
        const int col = n0 + wn + ni*16 + fr;
        const int c = col >> 6, khh = (col>>3)&7, kww = col&7;
        #pragma unroll
        for (int r = 0; r < 4; ++r){
          const int row = m0 + wm + mi*16 + fo*4 + r;
          const int hb = row >> 5, wbb = row & 31;
          O[(((long)bI*65536 + (hb*8+khh)*256 + wbb*8 + kww)<<6) + c] = f2bf(acc[mi][ni][r]);
        }
      }
  } else {
    // bf16 C + fused BN stats (per-column sum/sumsq via in-reg reduce + atomics)
    u16* Cb = (u16*)Cv + (long)bI*sC;
    #pragma unroll
    for (int mi = 0; mi < 4; ++mi)
      #pragma unroll
      for (int ni = 0; ni < 4; ++ni){
        const int col = n0 + wn + ni*16 + fr;
        #pragma unroll
        for (int r = 0; r < 4; ++r){
          const int row = m0 + wm + mi*16 + fo*4 + r;
          Cb[(long)row*N + col] = f2bf(acc[mi][ni][r]);
        }
      }
    const int sel = bI >> 2;
    float* sums = bnstats + sel*2048;
    #pragma unroll
    for (int ni = 0; ni < 4; ++ni){
      float s = 0.f, q = 0.f;
      #pragma unroll
      for (int mi = 0; mi < 4; ++mi)
        #pragma unroll
        for (int r = 0; r < 4; ++r){
          const float v = acc[mi][ni][r];
          s += v; q += v*v;
        }
      s += __shfl_xor(s, 16); s += __shfl_xor(s, 32);
      q += __shfl_xor(q, 16); q += __shfl_xor(q, 32);
      if (fo == 0){
        const int col = n0 + wn + ni*16 + fr;
        atomicAdd(&sums[col], s);
        atomicAdd(&sums[1024 + col], q);
      }
    }
  }
}

// ---------------------------------------------------------------------------
// ff1: C[262144][256] = X[262144][64] * W1b^T, bias+GELU, bf16 out. No LDS.
// ---------------------------------------------------------------------------
__global__ __launch_bounds__(256,3) void ff1_mfma(
    const u16* __restrict__ X, const u16* __restrict__ W1b,
    const float* __restrict__ B1, u16* __restrict__ H1)
{
  const int t = threadIdx.x, lane = t & 63, wv = t >> 6;
  const long m0 = (long)blockIdx.x*128 + (wv>>1)*64;
  const int n0 = blockIdx.y*128 + (wv&1)*64;
  const int fr = lane & 15, fo = lane >> 4;
  f32x4 acc[4][4] = {};
  #pragma unroll
  for (int k0 = 0; k0 < 64; k0 += 32){
    bf16x8 af[4], bfv[4];
    #pragma unroll
    for (int i = 0; i < 4; ++i){
      af[i]  = *(const bf16x8*)(X   + (m0 + i*16 + fr)*64 + k0 + fo*8);
      bfv[i] = *(const bf16x8*)(W1b + (long)(n0 + i*16 + fr)*64 + k0 + fo*8);
    }
    #pragma unroll
    for (int mi = 0; mi < 4; ++mi)
      #pragma unroll
      for (int ni = 0; ni < 4; ++ni)
        acc[mi][ni] = __builtin_amdgcn_mfma_f32_16x16x32_bf16(af[mi], bfv[ni], acc[mi][ni], 0, 0, 0);
  }
  #pragma unroll
  for (int ni = 0; ni < 4; ++ni){
    const int col = n0 + ni*16 + fr;
    const float bc = B1[col];
    #pragma unroll
    for (int mi = 0; mi < 4; ++mi){
      const long row = m0 + mi*16 + fo*4;
      #pragma unroll
      for (int r = 0; r < 4; ++r)
        H1[(row + r)*256 + col] = f2bf(gelu_f(acc[mi][ni][r] + bc));
    }
  }
}

// ---------------------------------------------------------------------------
// ff2: C[262144][64] = H1[262144][256] * W2b^T, bias+GELU+residual, fp32 NCHW.
// ---------------------------------------------------------------------------
__global__ __launch_bounds__(256,3) void ff2_mfma(
    const u16* __restrict__ H1, const u16* __restrict__ W2b,
    const float* __restrict__ B2, const float* __restrict__ F,
    float* __restrict__ OUT)
{
  const int t = threadIdx.x, lane = t & 63, wv = t >> 6;
  const long m0 = (long)blockIdx.x*256 + wv*64;
  const int fr = lane & 15, fo = lane >> 4;
  f32x4 acc[4][4] = {};
  for (int k0 = 0; k0 < 256; k0 += 32){
    bf16x8 af[4], bfv[4];
    #pragma unroll
    for (int i = 0; i < 4; ++i){
      af[i]  = *(const bf16x8*)(H1  + (m0 + i*16 + fr)*256 + k0 + fo*8);
      bfv[i] = *(const bf16x8*)(W2b + (long)(i*16 + fr)*256 + k0 + fo*8);
    }
    #pragma unroll
    for (int mi = 0; mi < 4; ++mi)
      #pragma unroll
      for (int ni = 0; ni < 4; ++ni)
        acc[mi][ni] = __builtin_amdgcn_mfma_f32_16x16x32_bf16(af[mi], bfv[ni], acc[mi][ni], 0, 0, 0);
  }
  #pragma unroll
  for (int ni = 0; ni < 4; ++ni){
    const int c = ni*16 + fr;
    const float bc = B2[c];
    #pragma unroll
    for (int mi = 0; mi < 4; ++mi){
      const long p = m0 + mi*16 + fo*4;
      const int b = (int)(p >> 16), pp = (int)(p & 65535);
      const long idx = ((long)(b*64 + c))*65536 + pp;
      const f4 fres = *(const f4*)&F[idx];
      f4 o;
      #pragma unroll
      for (int r = 0; r < 4; ++r) o[r] = gelu_f(acc[mi][ni][r] + bc) + fres[r];
      *(f4*)&OUT[idx] = o;
    }
  }
}

// ---------------------------------------------------------------------------
__global__ __launch_bounds__(256) void cvt_w(
    const float* __restrict__ Wq, const float* __restrict__ Wk,
    u16* __restrict__ Oq, u16* __restrict__ Ok)
{
  const long i = ((long)blockIdx.x*256 + threadIdx.x)*4;
  const float* s = blockIdx.y ? Wk : Wq;
  u16* d = blockIdx.y ? Ok : Oq;
  f4 v = *(const f4*)&s[i];
  u16x4 o; o[0]=f2bf(v[0]); o[1]=f2bf(v[1]); o[2]=f2bf(v[2]); o[3]=f2bf(v[3]);
  *(u16x4*)&d[i] = o;
}

__global__ __launch_bounds__(256) void cvt_ffw(
    const float* __restrict__ W1, const float* __restrict__ W2,
    u16* __restrict__ O1, u16* __restrict__ O2)
{
  const long i = ((long)blockIdx.x*256 + threadIdx.x)*4;
  const float* s = blockIdx.y ? W2 : W1;
  u16* d = blockIdx.y ? O2 : O1;
  f4 v = *(const f4*)&s[i];
  u16x4 o; o[0]=f2bf(v[0]); o[1]=f2bf(v[1]); o[2]=f2bf(v[2]); o[3]=f2bf(v[3]);
  *(u16x4*)&d[i] = o;
}

// ---------------------------------------------------------------------------
// BN finalize (stats from fused GEMM epilogue) and apply (bf16 in/out).
// ---------------------------------------------------------------------------
__global__ void bn_fin2(float* __restrict__ stats,
                        const float* __restrict__ gq, const float* __restrict__ bq,
                        const float* __restrict__ gk, const float* __restrict__ bk)
{
  const int sel = blockIdx.y;
  const int d = blockIdx.x*256 + threadIdx.x;
  if (d >= 1024) return;
  const float* sum   = stats + sel*2048;
  const float* sumsq = sum + 1024;
  const float* g    = sel ? gk : gq;
  const float* beta = sel ? bk : bq;
  const float m  = sum[d]   * (1.f/4096.f);
  const float vv = sumsq[d] * (1.f/4096.f) - m*m;
  const float sc = g[d] * rsqrtf(vv + 1e-5f);
  stats[4096 + sel*2048 + d]        = sc;
  stats[4096 + sel*2048 + 1024 + d] = beta[d] - m*sc;
}

__global__ __launch_bounds__(256) void bn_apply2(
    const u16* __restrict__ Xq, const float* __restrict__ stats,
    u16* __restrict__ Yq)
{
  const int sel = blockIdx.y;
  const u16* X = Xq + (long)sel*4194304;
  const float* scale = stats + 4096 + sel*2048;
  const float* shift = scale + 1024;
  const long i = ((long)blockIdx.x*256 + threadIdx.x)*4;
  u16x4 xv = *(const u16x4*)&X[i];
  const int d = (int)(i & 1023);
  const f4 sc = *(const f4*)&scale[d];
  const f4 sh = *(const f4*)&shift[d];
  u16x4 o;
  #pragma unroll
  for (int j = 0; j < 4; ++j) o[j] = f2bf(bf2f(xv[j])*sc[j] + sh[j]);
  *(u16x4*)&Yq[(long)sel*4194304 + i] = o;
}

__global__ __launch_bounds__(256) void softmax_k(
    const float* __restrict__ S, u16* __restrict__ P)
{
  const long row = blockIdx.x;
  const float* p = S + row*1024;
  const int t = threadIdx.x;
  f4 v = *(const f4*)&p[t*4];
  v *= 0.03125f;
  float mx = fmaxf(fmaxf(v[0],v[1]), fmaxf(v[2],v[3]));
  #pragma unroll
  for (int o = 1; o < 64; o <<= 1) mx = fmaxf(mx, __shfl_xor(mx, o));
  __shared__ float red[4], red2[4];
  if ((t & 63) == 0) red[t>>6] = mx;
  __syncthreads();
  mx = fmaxf(fmaxf(red[0],red[1]), fmaxf(red[2],red[3]));
  f4 e;
  e[0]=__expf(v[0]-mx); e[1]=__expf(v[1]-mx); e[2]=__expf(v[2]-mx); e[3]=__expf(v[3]-mx);
  float sm = e[0]+e[1]+e[2]+e[3];
  #pragma unroll
  for (int o = 1; o < 64; o <<= 1) sm += __shfl_xor(sm, o);
  if ((t & 63) == 0) red2[t>>6] = sm;
  __syncthreads();
  sm = red2[0]+red2[1]+red2[2]+red2[3];
  const float inv = 1.0f/sm;
  u16x4 o4; o4[0]=f2bf(e[0]*inv); o4[1]=f2bf(e[1]*inv); o4[2]=f2bf(e[2]*inv); o4[3]=f2bf(e[3]*inv);
  *(u16x4*)&P[row*1024 + t*4] = o4;
}

// ---------------------------------------------------------------------------
extern "C" void kernel_launch(void* const* d_in, const int* in_sizes, int n_in,
                              void* d_out, int out_size, void* d_ws, size_t ws_size,
                              hipStream_t stream)
{
  const float* feat  = (const float*)d_in[0];
  const float* w_enc = (const float*)d_in[1];
  const float* b_enc = (const float*)d_in[2];
  const float* w_k   = (const float*)d_in[3];
  const float* b_k   = (const float*)d_in[4];
  const float* w_v   = (const float*)d_in[5];
  const float* b_v   = (const float*)d_in[6];
  const float* fcq_w = (const float*)d_in[7];
  // d_in[8] fcq_b, d_in[10] fck_b: cancelled exactly by train-mode BN.
  const float* fck_w = (const float*)d_in[9];
  const float* bnq_g = (const float*)d_in[11];
  const float* bnq_b = (const float*)d_in[12];
  const float* bnk_g = (const float*)d_in[13];
  const float* bnk_b = (const float*)d_in[14];
  const float* ff1w  = (const float*)d_in[15];
  const float* ff1b  = (const float*)d_in[16];
  const float* ff2w  = (const float*)d_in[17];
  const float* ff2b  = (const float*)d_in[18];

  char* ws = (char*)d_ws;
  u16*   Aq      = (u16*)  (ws);                   // [0,32)  MB [B][L][4096] (Ak follows)
  u16*   Ak      = (u16*)  (ws + (32ull<<20));     // [32,64)
  u16*   Vc      = (u16*)  (ws + (64ull<<20));     // [64,96)  [B][4096][L]
  u16*   Wq      = (u16*)  (ws + (96ull<<20));     // [96,104)  (Wk follows)
  u16*   Wk      = (u16*)  (ws + (104ull<<20));    // [104,112)
  u16*   q_bf    = (u16*)  (ws + (112ull<<20));    // [112,120) (k_bf follows)
  u16*   k_bf    = (u16*)  (ws + (120ull<<20));    // [120,128)
  u16*   qk_raw  = (u16*)  (ws + (128ull<<20));    // [128,144) bf16 pre-BN q|k (8 z-slices)
  float* scores  = (float*)(ws + (160ull<<20));    // [160,176)
  u16*   attn    = (u16*)  (ws + (176ull<<20));    // [176,184)
  u16*   out_nhwc= (u16*)  (ws + (184ull<<20));    // [184,216) [B][65536][64]
  u16*   NX      = (u16*)  (ws + (128ull<<20));    // [128,160) transient (dead before qk_raw)
  u16*   Vl      = (u16*)  (ws + (160ull<<20));    // [160,192) transient (dead before scores)
  u16*   Wt2     = (u16*)  (ws + (216ull<<20));    // +221KB
  float* stats   = (float*)(ws + (217ull<<20));    // 32KB
  u16*   W1b     = (u16*)  (ws + (218ull<<20));    // 32KB [256][64] bf16
  u16*   W2b     = (u16*)  (ws + (218ull<<20) + 65536); // 32KB [64][256] bf16
  u16*   h1      = (u16*)  (ws);                   // [0,128) reuse (Aq..k_bf dead by ff1)

  hipMemsetAsync(stats, 0, 4096*sizeof(float), stream);

  to_nhwc<<<dim3(1024,4), 256, 0, stream>>>(feat, NX);
  wt_prep<<<dim3(432), 256, 0, stream>>>(w_enc, w_k, w_v, Wt2);
  conv_mfma<<<dim3(16,64,4), 256, 0, stream>>>(NX, Wt2, b_enc, b_k, b_v, Aq, Ak, Vl);
  v_tr<<<dim3(64,16,4), 256, 0, stream>>>(Vl, Vc);
  cvt_w<<<dim3(4096,2), 256, 0, stream>>>(fcq_w, fck_w, Wq, Wk);
  cvt_ffw<<<dim3(16,2), 256, 0, stream>>>(ff1w, ff2w, W1b, W2b);

  // merged q+k projections (z 0..3: q, 4..7: k), bf16 C + fused BN stats
  gemm_bt<2><<<dim3(8,8,8),  256, 0, stream>>>(Aq, 4194304, Wq, 4194304, 2,
                                               qk_raw, 1048576, 1024, 1024, 4096, stats);

  bn_fin2<<<dim3(4,2), 256, 0, stream>>>(stats, bnq_g, bnq_b, bnk_g, bnk_b);
  bn_apply2<<<dim3(4096,2), 256, 0, stream>>>(qk_raw, stats, q_bf);

  gemm_bt<0><<<dim3(8,8,4),  256, 0, stream>>>(q_bf, 1048576, k_bf, 1048576, 0,
                                               scores, 1048576, 1024, 1024, 1024, nullptr);
  softmax_k<<<dim3(4096), 256, 0, stream>>>(scores, attn);

  gemm_bt<1><<<dim3(8,32,4), 256, 0, stream>>>(attn, 1048576, Vc, 4194304, 0,
                                               out_nhwc, 0, 1024, 4096, 1024, nullptr);

  ff1_mfma<<<dim3(2048,2), 256, 0, stream>>>(out_nhwc, W1b, ff1b, h1);
  ff2_mfma<<<dim3(1024), 256, 0, stream>>>(h1, W2b, ff2b, feat, (float*)d_out);
}